// Round 1
// baseline (263.928 us; speedup 1.0000x reference)
//
#include <hip/hip_runtime.h>
#include <hip/hip_bf16.h>

#define B_ 64
#define T_ 1024
#define D_ 256
#define K_ 128

__device__ __forceinline__ float san(float v) {
    if (isnan(v)) return 0.0f;
    if (isinf(v)) return v > 0.0f ? 1e4f : -1e4f;
    return v;
}

__device__ __forceinline__ float4 san4(float4 f) {
    f.x = san(f.x); f.y = san(f.y); f.z = san(f.z); f.w = san(f.w);
    return f;
}

// ---------------------------------------------------------------------------
// Kernel 1: sanitize + (deferred) L2-normalize + projection GEMM.
// Tile: 128 tokens x 128 projections, BK=32, 256 threads, 8x8 per thread.
// Output layout: out[z][b][k][t]  (z=0 -> xp, z=1 -> yp)
// ---------------------------------------------------------------------------
__global__ __launch_bounds__(256, 4)
void proj_kernel(const float* __restrict__ xin, const float* __restrict__ yin,
                 const float* __restrict__ proj, float* __restrict__ outp) {
    __shared__ float At[32 * 132];   // A-tile transposed: At[d][t], row pad 132
    __shared__ float Bs[32 * 132];   // B-tile: Bs[d][k], row pad 132
    __shared__ float rn[128];        // per-token 1/max(norm, eps)

    const int tid   = threadIdx.x;
    const int ttile = blockIdx.x;    // 0..7   (128-token tiles)
    const int b     = blockIdx.y;    // 0..63
    const int z     = blockIdx.z;    // 0 = x, 1 = y

    const float* src = (z == 0 ? xin : yin)
                     + (size_t)b * (T_ * D_) + (size_t)ttile * 128 * D_;

    // ---- phase 0: token norms (2 threads per token) ----
    {
        const int t = tid >> 1, h = tid & 1;
        const float* p = src + t * D_ + h * 128;
        float s = 0.0f;
        #pragma unroll
        for (int i = 0; i < 32; ++i) {
            float4 f = san4(*(const float4*)(p + i * 4));
            s += f.x * f.x + f.y * f.y + f.z * f.z + f.w * f.w;
        }
        s += __shfl_xor(s, 1);
        if (h == 0) rn[t] = 1.0f / fmaxf(sqrtf(s), 1e-6f);
    }
    __syncthreads();

    float acc[8][8] = {};
    const int tg = tid >> 4, kg = tid & 15;
    const int t_base = tg * 8, k_base = kg * 8;

    for (int ds = 0; ds < 8; ++ds) {
        // stage A transposed (sanitized)
        #pragma unroll
        for (int it = 0; it < 4; ++it) {
            int q = it * 256 + tid;              // 0..1023 float4 slots
            int t = q >> 3, dq = (q & 7) << 2;
            float4 f = san4(*(const float4*)(src + t * D_ + ds * 32 + dq));
            At[(dq + 0) * 132 + t] = f.x;
            At[(dq + 1) * 132 + t] = f.y;
            At[(dq + 2) * 132 + t] = f.z;
            At[(dq + 3) * 132 + t] = f.w;
        }
        // stage B
        #pragma unroll
        for (int it = 0; it < 4; ++it) {
            int q = it * 256 + tid;
            int d = q >> 5, k4 = (q & 31) << 2;
            float4 f = *(const float4*)(proj + (size_t)(ds * 32 + d) * K_ + k4);
            *(float4*)&Bs[d * 132 + k4] = f;
        }
        __syncthreads();

        #pragma unroll 4
        for (int d = 0; d < 32; ++d) {
            float4 a0 = *(float4*)&At[d * 132 + t_base];
            float4 a1 = *(float4*)&At[d * 132 + t_base + 4];
            float4 b0 = *(float4*)&Bs[d * 132 + k_base];
            float4 b1 = *(float4*)&Bs[d * 132 + k_base + 4];
            float a[8] = {a0.x, a0.y, a0.z, a0.w, a1.x, a1.y, a1.z, a1.w};
            float bb[8] = {b0.x, b0.y, b0.z, b0.w, b1.x, b1.y, b1.z, b1.w};
            #pragma unroll
            for (int i = 0; i < 8; ++i)
                #pragma unroll
                for (int j = 0; j < 8; ++j)
                    acc[i][j] += a[i] * bb[j];
        }
        __syncthreads();
    }

    // ---- epilogue: apply 1/norm, store (B,K,T) ----
    float* out = outp + (size_t)z * ((size_t)B_ * K_ * T_) + (size_t)b * (K_ * T_);
    const int t0 = ttile * 128 + t_base;
    #pragma unroll
    for (int i = 0; i < 8; ++i) {
        float r = rn[t_base + i];
        #pragma unroll
        for (int j = 0; j < 8; ++j) acc[i][j] *= r;
    }
    #pragma unroll
    for (int j = 0; j < 8; ++j) {
        float4 v0 = make_float4(acc[0][j], acc[1][j], acc[2][j], acc[3][j]);
        float4 v1 = make_float4(acc[4][j], acc[5][j], acc[6][j], acc[7][j]);
        float* dst = out + (size_t)(k_base + j) * T_ + t0;
        *(float4*)&dst[0] = v0;
        *(float4*)&dst[4] = v1;
    }
}

// ---------------------------------------------------------------------------
// Kernel 2: per-wave register bitonic sort of 1024 floats (16/lane) for both
// xp and yp rows of one (b,k), then sum of squared sorted differences.
// Element id e = lane*16 + r. Intra-lane strides (j<16) are register CEs,
// cross-lane strides (j=16m) use __shfl_xor.
// ---------------------------------------------------------------------------
__device__ __forceinline__ void ce_cross(float vx[16], float vy[16],
                                         int lane, int M, int K) {
    const bool left = (lane & M) == 0;
    const bool up = (((lane << 4) & K) == 0);
    const bool keepmin = (left == up);
    #pragma unroll
    for (int r = 0; r < 16; ++r) {
        float ox = __shfl_xor(vx[r], M);
        vx[r] = keepmin ? fminf(vx[r], ox) : fmaxf(vx[r], ox);
        float oy = __shfl_xor(vy[r], M);
        vy[r] = keepmin ? fminf(vy[r], oy) : fmaxf(vy[r], oy);
    }
}

template <int J>
__device__ __forceinline__ void ce_intra(float vx[16], float vy[16],
                                         int lane, int K) {
    #pragma unroll
    for (int r = 0; r < 16; ++r) {
        if ((r & J) == 0) {                    // compile-time folded
            const int p = r | J;
            const bool up = ((((lane << 4) | r) & K) == 0);
            float ax = vx[r], bx = vx[p];
            float lox = fminf(ax, bx), hix = fmaxf(ax, bx);
            vx[r] = up ? lox : hix;
            vx[p] = up ? hix : lox;
            float ay = vy[r], by = vy[p];
            float loy = fminf(ay, by), hiy = fmaxf(ay, by);
            vy[r] = up ? loy : hiy;
            vy[p] = up ? hiy : loy;
        }
    }
}

__global__ __launch_bounds__(256)
void sort_cost_kernel(const float* __restrict__ ws, float* __restrict__ cost) {
    const int wid  = threadIdx.x >> 6;
    const int lane = threadIdx.x & 63;
    const int bk   = blockIdx.x * 4 + wid;             // 0..8191

    const float* xr = ws + (size_t)bk * T_;
    const float* yr = ws + (size_t)(B_ * K_) * T_ + (size_t)bk * T_;

    float vx[16], vy[16];
    #pragma unroll
    for (int i = 0; i < 4; ++i) {
        float4 f = *(const float4*)(xr + lane * 16 + i * 4);
        vx[i * 4 + 0] = f.x; vx[i * 4 + 1] = f.y;
        vx[i * 4 + 2] = f.z; vx[i * 4 + 3] = f.w;
        float4 g = *(const float4*)(yr + lane * 16 + i * 4);
        vy[i * 4 + 0] = g.x; vy[i * 4 + 1] = g.y;
        vy[i * 4 + 2] = g.z; vy[i * 4 + 3] = g.w;
    }

    // bitonic sort, ascending over e = lane*16 + r
    ce_intra<1>(vx, vy, lane, 2);
    ce_intra<2>(vx, vy, lane, 4);
    ce_intra<1>(vx, vy, lane, 4);
    ce_intra<4>(vx, vy, lane, 8);
    ce_intra<2>(vx, vy, lane, 8);
    ce_intra<1>(vx, vy, lane, 8);
    for (int k = 16; k <= 1024; k <<= 1) {
        for (int j = k >> 1; j >= 16; j >>= 1)
            ce_cross(vx, vy, lane, j >> 4, k);
        ce_intra<8>(vx, vy, lane, k);
        ce_intra<4>(vx, vy, lane, k);
        ce_intra<2>(vx, vy, lane, k);
        ce_intra<1>(vx, vy, lane, k);
    }

    float s = 0.0f;
    #pragma unroll
    for (int r = 0; r < 16; ++r) {
        float d = vx[r] - vy[r];
        s += d * d;
    }
    #pragma unroll
    for (int m = 1; m <= 32; m <<= 1) s += __shfl_xor(s, m);
    if (lane == 0) cost[bk] = s;
}

// ---------------------------------------------------------------------------
// Kernel 3: sw[b] = sanitize(sqrt(sum_k cost / (K*T)))
// ---------------------------------------------------------------------------
__global__ void finalize_kernel(const float* __restrict__ cost,
                                float* __restrict__ out) {
    const int b = threadIdx.x;
    if (b >= B_) return;
    float s = 0.0f;
    for (int k = 0; k < K_; ++k) s += cost[b * K_ + k];
    float sw = sqrtf(s * (1.0f / (float)(K_ * T_)));
    if (isnan(sw)) sw = 1e4f;
    else if (isinf(sw)) sw = sw > 0.0f ? 1e4f : 0.0f;
    out[b] = sw;
}

extern "C" void kernel_launch(void* const* d_in, const int* in_sizes, int n_in,
                              void* d_out, int out_size, void* d_ws, size_t ws_size,
                              hipStream_t stream) {
    const float* x    = (const float*)d_in[0];
    const float* y    = (const float*)d_in[1];
    const float* proj = (const float*)d_in[2];
    float* wsf  = (float*)d_ws;
    float* cost = wsf + (size_t)2 * B_ * K_ * T_;   // after xp and yp (64 MB)
    float* out  = (float*)d_out;

    proj_kernel<<<dim3(8, B_, 2), 256, 0, stream>>>(x, y, proj, wsf);
    sort_cost_kernel<<<(B_ * K_) / 4, 256, 0, stream>>>(wsf, cost);
    finalize_kernel<<<1, 64, 0, stream>>>(cost, out);
}

// Round 4
// 162.743 us; speedup vs baseline: 1.6218x; 1.6218x over previous
//
#include <hip/hip_runtime.h>
#include <hip/hip_bf16.h>

#define B_ 64
#define T_ 1024
#define D_ 256
#define K_ 128

typedef __attribute__((ext_vector_type(8))) short bf16x8;
typedef __attribute__((ext_vector_type(4))) float f32x4;

__device__ __forceinline__ float san(float v) {
    if (isnan(v)) return 0.0f;
    if (isinf(v)) return v > 0.0f ? 1e4f : -1e4f;
    return v;
}

__device__ __forceinline__ float4 san4(float4 f) {
    f.x = san(f.x); f.y = san(f.y); f.z = san(f.z); f.w = san(f.w);
    return f;
}

// RNE float->bf16 (inputs pre-sanitized: no NaN/Inf)
__device__ __forceinline__ unsigned int f2bf(float f) {
    unsigned int u = __builtin_bit_cast(unsigned int, f);
    u += 0x7fffu + ((u >> 16) & 1u);
    return u >> 16;
}

// ---------------------------------------------------------------------------
// Kernel 0: proj (D,K) fp32 -> projT (K,D) bf16  (tiny one-time transpose)
// ---------------------------------------------------------------------------
__global__ void transpose_proj_kernel(const float* __restrict__ proj,
                                      unsigned short* __restrict__ pt) {
    int e = blockIdx.x * 256 + threadIdx.x;       // 32768 elems
    if (e < D_ * K_) {
        int d = e >> 7, k = e & 127;
        pt[k * D_ + d] = (unsigned short)f2bf(proj[e]);
    }
}

// ---------------------------------------------------------------------------
// Kernel 1: fused sanitize + bf16 MFMA projection + deferred L2-normalize.
// Block: 256 threads (4 waves), tile = 128 tokens x 128 projections.
// d split in 2 chunks of 128 (LDS 64KB -> 2 blocks/CU).
// Per wave: 32 tokens x 128 k  (2 m-tiles x 8 n-tiles of 16x16x32 MFMA).
// LDS tiles row-major [row][128 d] bf16 with byte-swizzle ^((row&7)<<4).
// k-slot mapping identical for A and P frags => hardware k-order cancels.
// Output layout: out[z][b][k][t]  fp32.
// ---------------------------------------------------------------------------
__global__ __launch_bounds__(256, 2)
void proj_kernel(const float* __restrict__ xin, const float* __restrict__ yin,
                 const unsigned short* __restrict__ pt, float* __restrict__ outp) {
    __shared__ short As[128 * 128];   // 32 KB: tokens x d-chunk (bf16, swizzled)
    __shared__ short Ps[128 * 128];   // 32 KB: k x d-chunk (bf16, swizzled)
    __shared__ float rnacc[128];      // per-token sum of squares -> 1/norm

    const int tid  = threadIdx.x;
    const int lane = tid & 63;
    const int w    = tid >> 6;        // wave 0..3
    const int ttile = blockIdx.x;     // 0..7
    const int b     = blockIdx.y;     // 0..63
    const int z     = blockIdx.z;     // 0=x 1=y

    const float* src = (z == 0 ? xin : yin)
                     + (size_t)b * (T_ * D_) + (size_t)ttile * 128 * D_;

    f32x4 acc[2][8];
    #pragma unroll
    for (int i = 0; i < 2; ++i)
        #pragma unroll
        for (int j = 0; j < 8; ++j)
            acc[i][j] = (f32x4){0.f, 0.f, 0.f, 0.f};

    const int l15 = lane & 15;
    const int l4  = lane >> 4;

    for (int c = 0; c < 2; ++c) {
        // ---- stage A chunk (128 t x 128 d fp32 -> bf16 LDS) + norm partials
        #pragma unroll
        for (int i = 0; i < 16; ++i) {
            int q  = i * 256 + tid;
            int t  = q >> 5;           // 32 float4 per row-chunk
            int d4 = q & 31;
            float4 f = san4(*(const float4*)(src + t * D_ + c * 128 + d4 * 4));
            float ssq = f.x * f.x + f.y * f.y + f.z * f.z + f.w * f.w;
            ssq += __shfl_xor(ssq, 1);
            ssq += __shfl_xor(ssq, 2);
            ssq += __shfl_xor(ssq, 4);
            ssq += __shfl_xor(ssq, 8);
            ssq += __shfl_xor(ssq, 16);
            if (d4 == 0) {
                if (c == 0) rnacc[t] = ssq;
                else        rnacc[t] += ssq;
            }
            uint2 p;
            p.x = f2bf(f.x) | (f2bf(f.y) << 16);
            p.y = f2bf(f.z) | (f2bf(f.w) << 16);
            int byteoff = (t * 256 + d4 * 8) ^ ((t & 7) << 4);
            *(uint2*)((char*)As + byteoff) = p;
        }
        // ---- stage P chunk (128 k x 128 d bf16, already transposed)
        #pragma unroll
        for (int i = 0; i < 8; ++i) {
            int q  = i * 256 + tid;
            int k  = q >> 4;           // 16 x (8 bf16) per row-chunk
            int d8 = q & 15;
            uint4 v = *(const uint4*)(pt + k * D_ + c * 128 + d8 * 8);
            int byteoff = (k * 256 + d8 * 16) ^ ((k & 7) << 4);
            *(uint4*)((char*)Ps + byteoff) = v;
        }
        __syncthreads();

        // ---- MFMA: 4 k-steps of 32 d
        #pragma unroll
        for (int ks = 0; ks < 4; ++ks) {
            const int kb = ks * 32;
            bf16x8 af[2];
            #pragma unroll
            for (int mt = 0; mt < 2; ++mt) {
                int t = w * 32 + mt * 16 + l15;
                int byteoff = (t * 256 + kb * 2 + l4 * 16) ^ ((t & 7) << 4);
                af[mt] = *(bf16x8*)((char*)As + byteoff);
            }
            bf16x8 pf[8];
            #pragma unroll
            for (int nt = 0; nt < 8; ++nt) {
                int k = nt * 16 + l15;
                int byteoff = (k * 256 + kb * 2 + l4 * 16) ^ ((k & 7) << 4);
                pf[nt] = *(bf16x8*)((char*)Ps + byteoff);
            }
            #pragma unroll
            for (int mt = 0; mt < 2; ++mt)
                #pragma unroll
                for (int nt = 0; nt < 8; ++nt)
                    acc[mt][nt] = __builtin_amdgcn_mfma_f32_16x16x32_bf16(
                        af[mt], pf[nt], acc[mt][nt], 0, 0, 0);
        }
        __syncthreads();   // protect LDS before next chunk restage
    }

    // ---- finalize 1/norm
    if (tid < 128) rnacc[tid] = 1.0f / fmaxf(sqrtf(rnacc[tid]), 1e-6f);
    __syncthreads();

    // ---- epilogue: scale rows by 1/norm, store out[k][t]
    // C layout (verified): col = k = lane&15, row = t = (lane>>4)*4 + reg
    float* out = outp + (size_t)z * ((size_t)B_ * K_ * T_) + (size_t)b * (K_ * T_);
    #pragma unroll
    for (int mt = 0; mt < 2; ++mt) {
        const int tl = w * 32 + mt * 16 + l4 * 4;        // local token base
        const int tg = ttile * 128 + tl;                 // global t base
        float r0 = rnacc[tl + 0], r1 = rnacc[tl + 1];
        float r2 = rnacc[tl + 2], r3 = rnacc[tl + 3];
        #pragma unroll
        for (int nt = 0; nt < 8; ++nt) {
            int k = nt * 16 + l15;
            float4 v;
            v.x = acc[mt][nt][0] * r0;
            v.y = acc[mt][nt][1] * r1;
            v.z = acc[mt][nt][2] * r2;
            v.w = acc[mt][nt][3] * r3;
            *(float4*)(out + (size_t)k * T_ + tg) = v;
        }
    }
}

// ---------------------------------------------------------------------------
// Kernel 2: per-wave register bitonic sort of 1024 floats (16/lane) for both
// xp and yp rows of one (b,k), then sum of squared sorted differences.
// ---------------------------------------------------------------------------
__device__ __forceinline__ void ce_cross(float vx[16], float vy[16],
                                         int lane, int M, int K) {
    const bool left = (lane & M) == 0;
    const bool up = (((lane << 4) & K) == 0);
    const bool keepmin = (left == up);
    #pragma unroll
    for (int r = 0; r < 16; ++r) {
        float ox = __shfl_xor(vx[r], M);
        vx[r] = keepmin ? fminf(vx[r], ox) : fmaxf(vx[r], ox);
        float oy = __shfl_xor(vy[r], M);
        vy[r] = keepmin ? fminf(vy[r], oy) : fmaxf(vy[r], oy);
    }
}

template <int J>
__device__ __forceinline__ void ce_intra(float vx[16], float vy[16],
                                         int lane, int K) {
    #pragma unroll
    for (int r = 0; r < 16; ++r) {
        if ((r & J) == 0) {
            const int p = r | J;
            const bool up = ((((lane << 4) | r) & K) == 0);
            float ax = vx[r], bx = vx[p];
            float lox = fminf(ax, bx), hix = fmaxf(ax, bx);
            vx[r] = up ? lox : hix;
            vx[p] = up ? hix : lox;
            float ay = vy[r], by = vy[p];
            float loy = fminf(ay, by), hiy = fmaxf(ay, by);
            vy[r] = up ? loy : hiy;
            vy[p] = up ? hiy : loy;
        }
    }
}

__global__ __launch_bounds__(256)
void sort_cost_kernel(const float* __restrict__ ws, float* __restrict__ cost) {
    const int wid  = threadIdx.x >> 6;
    const int lane = threadIdx.x & 63;
    const int bk   = blockIdx.x * 4 + wid;             // 0..8191

    const float* xr = ws + (size_t)bk * T_;
    const float* yr = ws + (size_t)(B_ * K_) * T_ + (size_t)bk * T_;

    float vx[16], vy[16];
    #pragma unroll
    for (int i = 0; i < 4; ++i) {
        float4 f = *(const float4*)(xr + lane * 16 + i * 4);
        vx[i * 4 + 0] = f.x; vx[i * 4 + 1] = f.y;
        vx[i * 4 + 2] = f.z; vx[i * 4 + 3] = f.w;
        float4 g = *(const float4*)(yr + lane * 16 + i * 4);
        vy[i * 4 + 0] = g.x; vy[i * 4 + 1] = g.y;
        vy[i * 4 + 2] = g.z; vy[i * 4 + 3] = g.w;
    }

    ce_intra<1>(vx, vy, lane, 2);
    ce_intra<2>(vx, vy, lane, 4);
    ce_intra<1>(vx, vy, lane, 4);
    ce_intra<4>(vx, vy, lane, 8);
    ce_intra<2>(vx, vy, lane, 8);
    ce_intra<1>(vx, vy, lane, 8);
    for (int k = 16; k <= 1024; k <<= 1) {
        for (int j = k >> 1; j >= 16; j >>= 1)
            ce_cross(vx, vy, lane, j >> 4, k);
        ce_intra<8>(vx, vy, lane, k);
        ce_intra<4>(vx, vy, lane, k);
        ce_intra<2>(vx, vy, lane, k);
        ce_intra<1>(vx, vy, lane, k);
    }

    float s = 0.0f;
    #pragma unroll
    for (int r = 0; r < 16; ++r) {
        float d = vx[r] - vy[r];
        s += d * d;
    }
    #pragma unroll
    for (int m = 1; m <= 32; m <<= 1) s += __shfl_xor(s, m);
    if (lane == 0) cost[bk] = s;
}

// ---------------------------------------------------------------------------
// Kernel 3: sw[b] = sanitize(sqrt(sum_k cost / (K*T)))
// ---------------------------------------------------------------------------
__global__ void finalize_kernel(const float* __restrict__ cost,
                                float* __restrict__ out) {
    const int b = threadIdx.x;
    if (b >= B_) return;
    float s = 0.0f;
    for (int k = 0; k < K_; ++k) s += cost[b * K_ + k];
    float sw = sqrtf(s * (1.0f / (float)(K_ * T_)));
    if (isnan(sw)) sw = 1e4f;
    else if (isinf(sw)) sw = sw > 0.0f ? 1e4f : 0.0f;
    out[b] = sw;
}

extern "C" void kernel_launch(void* const* d_in, const int* in_sizes, int n_in,
                              void* d_out, int out_size, void* d_ws, size_t ws_size,
                              hipStream_t stream) {
    const float* x    = (const float*)d_in[0];
    const float* y    = (const float*)d_in[1];
    const float* proj = (const float*)d_in[2];
    float* wsf = (float*)d_ws;
    // ws layout: [xp|yp] 64 MB fp32, then projT bf16 (64 KB), then cost (32 KB)
    unsigned short* pt = (unsigned short*)(wsf + (size_t)2 * B_ * K_ * T_);
    float* cost = (float*)(pt + (size_t)K_ * D_);
    float* out  = (float*)d_out;

    transpose_proj_kernel<<<(D_ * K_ + 255) / 256, 256, 0, stream>>>(proj, pt);
    proj_kernel<<<dim3(8, B_, 2), 256, 0, stream>>>(x, y, pt, wsf);
    sort_cost_kernel<<<(B_ * K_) / 4, 256, 0, stream>>>(wsf, cost);
    finalize_kernel<<<1, 64, 0, stream>>>(cost, out);
}

// Round 8
// 145.788 us; speedup vs baseline: 1.8104x; 1.1163x over previous
//
#include <hip/hip_runtime.h>
#include <hip/hip_bf16.h>

#define B_ 64
#define T_ 1024
#define D_ 256
#define K_ 128

typedef __attribute__((ext_vector_type(8))) short bf16x8;
typedef __attribute__((ext_vector_type(4))) float f32x4;

__device__ __forceinline__ float san(float v) {
    if (isnan(v)) return 0.0f;
    if (isinf(v)) return v > 0.0f ? 1e4f : -1e4f;
    return v;
}

__device__ __forceinline__ float4 san4(float4 f) {
    f.x = san(f.x); f.y = san(f.y); f.z = san(f.z); f.w = san(f.w);
    return f;
}

// RNE float->bf16 (inputs pre-sanitized: no NaN/Inf)
__device__ __forceinline__ unsigned int f2bf(float f) {
    unsigned int u = __builtin_bit_cast(unsigned int, f);
    u += 0x7fffu + ((u >> 16) & 1u);
    return u >> 16;
}

// ---------------------------------------------------------------------------
// Kernel 0: proj (D,K) fp32 -> projT (K,D) bf16  (tiny one-time transpose)
// ---------------------------------------------------------------------------
__global__ void transpose_proj_kernel(const float* __restrict__ proj,
                                      unsigned short* __restrict__ pt) {
    int e = blockIdx.x * 256 + threadIdx.x;       // 32768 elems
    if (e < D_ * K_) {
        int d = e >> 7, k = e & 127;
        pt[k * D_ + d] = (unsigned short)f2bf(proj[e]);
    }
}

// ---------------------------------------------------------------------------
// Kernel 1: fused sanitize + bf16 MFMA projection + deferred L2-normalize.
// (unchanged from R4 — passed with absmax 0.0, ~55 us)
// ---------------------------------------------------------------------------
__global__ __launch_bounds__(256, 2)
void proj_kernel(const float* __restrict__ xin, const float* __restrict__ yin,
                 const unsigned short* __restrict__ pt, float* __restrict__ outp) {
    __shared__ short As[128 * 128];
    __shared__ short Ps[128 * 128];
    __shared__ float rnacc[128];

    const int tid  = threadIdx.x;
    const int lane = tid & 63;
    const int w    = tid >> 6;
    const int ttile = blockIdx.x;
    const int b     = blockIdx.y;
    const int z     = blockIdx.z;

    const float* src = (z == 0 ? xin : yin)
                     + (size_t)b * (T_ * D_) + (size_t)ttile * 128 * D_;

    f32x4 acc[2][8];
    #pragma unroll
    for (int i = 0; i < 2; ++i)
        #pragma unroll
        for (int j = 0; j < 8; ++j)
            acc[i][j] = (f32x4){0.f, 0.f, 0.f, 0.f};

    const int l15 = lane & 15;
    const int l4  = lane >> 4;

    for (int c = 0; c < 2; ++c) {
        #pragma unroll
        for (int i = 0; i < 16; ++i) {
            int q  = i * 256 + tid;
            int t  = q >> 5;
            int d4 = q & 31;
            float4 f = san4(*(const float4*)(src + t * D_ + c * 128 + d4 * 4));
            float ssq = f.x * f.x + f.y * f.y + f.z * f.z + f.w * f.w;
            ssq += __shfl_xor(ssq, 1);
            ssq += __shfl_xor(ssq, 2);
            ssq += __shfl_xor(ssq, 4);
            ssq += __shfl_xor(ssq, 8);
            ssq += __shfl_xor(ssq, 16);
            if (d4 == 0) {
                if (c == 0) rnacc[t] = ssq;
                else        rnacc[t] += ssq;
            }
            uint2 p;
            p.x = f2bf(f.x) | (f2bf(f.y) << 16);
            p.y = f2bf(f.z) | (f2bf(f.w) << 16);
            int byteoff = (t * 256 + d4 * 8) ^ ((t & 7) << 4);
            *(uint2*)((char*)As + byteoff) = p;
        }
        #pragma unroll
        for (int i = 0; i < 8; ++i) {
            int q  = i * 256 + tid;
            int k  = q >> 4;
            int d8 = q & 15;
            uint4 v = *(const uint4*)(pt + k * D_ + c * 128 + d8 * 8);
            int byteoff = (k * 256 + d8 * 16) ^ ((k & 7) << 4);
            *(uint4*)((char*)Ps + byteoff) = v;
        }
        __syncthreads();

        #pragma unroll
        for (int ks = 0; ks < 4; ++ks) {
            const int kb = ks * 32;
            bf16x8 af[2];
            #pragma unroll
            for (int mt = 0; mt < 2; ++mt) {
                int t = w * 32 + mt * 16 + l15;
                int byteoff = (t * 256 + kb * 2 + l4 * 16) ^ ((t & 7) << 4);
                af[mt] = *(bf16x8*)((char*)As + byteoff);
            }
            bf16x8 pf[8];
            #pragma unroll
            for (int nt = 0; nt < 8; ++nt) {
                int k = nt * 16 + l15;
                int byteoff = (k * 256 + kb * 2 + l4 * 16) ^ ((k & 7) << 4);
                pf[nt] = *(bf16x8*)((char*)Ps + byteoff);
            }
            #pragma unroll
            for (int mt = 0; mt < 2; ++mt)
                #pragma unroll
                for (int nt = 0; nt < 8; ++nt)
                    acc[mt][nt] = __builtin_amdgcn_mfma_f32_16x16x32_bf16(
                        af[mt], pf[nt], acc[mt][nt], 0, 0, 0);
        }
        __syncthreads();
    }

    if (tid < 128) rnacc[tid] = 1.0f / fmaxf(sqrtf(rnacc[tid]), 1e-6f);
    __syncthreads();

    float* out = outp + (size_t)z * ((size_t)B_ * K_ * T_) + (size_t)b * (K_ * T_);
    #pragma unroll
    for (int mt = 0; mt < 2; ++mt) {
        const int tl = w * 32 + mt * 16 + l4 * 4;
        const int tg = ttile * 128 + tl;
        float r0 = rnacc[tl + 0], r1 = rnacc[tl + 1];
        float r2 = rnacc[tl + 2], r3 = rnacc[tl + 3];
        #pragma unroll
        for (int nt = 0; nt < 8; ++nt) {
            int k = nt * 16 + l15;
            float4 v;
            v.x = acc[mt][nt][0] * r0;
            v.y = acc[mt][nt][1] * r1;
            v.z = acc[mt][nt][2] * r2;
            v.w = acc[mt][nt][3] * r3;
            *(float4*)(out + (size_t)k * T_ + tg) = v;
        }
    }
}

// ---------------------------------------------------------------------------
// Kernel 2: per-wave register bitonic sort, FULLY STATIC network.
// Element id e = lane*16 + r (1024 elems). Direction bit of block k:
// k<=8 -> register index (compile-time); k>=16 -> lane bit (hoisted bool).
// All shuffle masks are immediates.
// ---------------------------------------------------------------------------
#define CE_A(a, b) { float _lo = fminf(a, b), _hi = fmaxf(a, b); a = _lo; b = _hi; }
#define CE_D(a, b) { float _lo = fminf(a, b), _hi = fmaxf(a, b); a = _hi; b = _lo; }

// k = 2, 4, 8 : directions compile-time per register pair
__device__ __forceinline__ void pre8(float v[16]) {
    // k=2 (j=1)
    CE_A(v[0], v[1]);  CE_D(v[2], v[3]);  CE_A(v[4], v[5]);  CE_D(v[6], v[7]);
    CE_A(v[8], v[9]);  CE_D(v[10], v[11]); CE_A(v[12], v[13]); CE_D(v[14], v[15]);
    // k=4, j=2
    CE_A(v[0], v[2]);  CE_A(v[1], v[3]);  CE_D(v[4], v[6]);  CE_D(v[5], v[7]);
    CE_A(v[8], v[10]); CE_A(v[9], v[11]); CE_D(v[12], v[14]); CE_D(v[13], v[15]);
    // k=4, j=1
    CE_A(v[0], v[1]);  CE_A(v[2], v[3]);  CE_D(v[4], v[5]);  CE_D(v[6], v[7]);
    CE_A(v[8], v[9]);  CE_A(v[10], v[11]); CE_D(v[12], v[13]); CE_D(v[14], v[15]);
    // k=8, j=4
    CE_A(v[0], v[4]);  CE_A(v[1], v[5]);  CE_A(v[2], v[6]);  CE_A(v[3], v[7]);
    CE_D(v[8], v[12]); CE_D(v[9], v[13]); CE_D(v[10], v[14]); CE_D(v[11], v[15]);
    // k=8, j=2
    CE_A(v[0], v[2]);  CE_A(v[1], v[3]);  CE_A(v[4], v[6]);  CE_A(v[5], v[7]);
    CE_D(v[8], v[10]); CE_D(v[9], v[11]); CE_D(v[12], v[14]); CE_D(v[13], v[15]);
    // k=8, j=1
    CE_A(v[0], v[1]);  CE_A(v[2], v[3]);  CE_A(v[4], v[5]);  CE_A(v[6], v[7]);
    CE_D(v[8], v[9]);  CE_D(v[10], v[11]); CE_D(v[12], v[13]); CE_D(v[14], v[15]);
}

// intra-lane CE layer, per-lane direction `up`
template <int J>
__device__ __forceinline__ void intraU(float v[16], bool up) {
    #pragma unroll
    for (int r = 0; r < 16; ++r) {
        if ((r & J) == 0) {
            const int p = r | J;
            float lo = fminf(v[r], v[p]), hi = fmaxf(v[r], v[p]);
            v[r] = up ? lo : hi;
            v[p] = up ? hi : lo;
        }
    }
}

__device__ __forceinline__ void intra4U(float v[16], bool up) {
    intraU<8>(v, up); intraU<4>(v, up); intraU<2>(v, up); intraU<1>(v, up);
}

// final intra block (k=1024): ascending everywhere, no selects
__device__ __forceinline__ void intra4A(float v[16]) {
    CE_A(v[0], v[8]);  CE_A(v[1], v[9]);  CE_A(v[2], v[10]); CE_A(v[3], v[11]);
    CE_A(v[4], v[12]); CE_A(v[5], v[13]); CE_A(v[6], v[14]); CE_A(v[7], v[15]);
    CE_A(v[0], v[4]);  CE_A(v[1], v[5]);  CE_A(v[2], v[6]);  CE_A(v[3], v[7]);
    CE_A(v[8], v[12]); CE_A(v[9], v[13]); CE_A(v[10], v[14]); CE_A(v[11], v[15]);
    CE_A(v[0], v[2]);  CE_A(v[1], v[3]);  CE_A(v[4], v[6]);  CE_A(v[5], v[7]);
    CE_A(v[8], v[10]); CE_A(v[9], v[11]); CE_A(v[12], v[14]); CE_A(v[13], v[15]);
    CE_A(v[0], v[1]);  CE_A(v[2], v[3]);  CE_A(v[4], v[5]);  CE_A(v[6], v[7]);
    CE_A(v[8], v[9]);  CE_A(v[10], v[11]); CE_A(v[12], v[13]); CE_A(v[14], v[15]);
}

// cross-lane CE layer, immediate shuffle mask M, per-lane keepmin
template <int M>
__device__ __forceinline__ void crossU(float v[16], bool keepmin) {
    #pragma unroll
    for (int r = 0; r < 16; ++r) {
        float o  = __shfl_xor(v[r], M);
        float mn = fminf(v[r], o), mx = fmaxf(v[r], o);
        v[r] = keepmin ? mn : mx;
    }
}

__global__ __launch_bounds__(256)
void sort_cost_kernel(const float* __restrict__ ws, float* __restrict__ cost) {
    const int wid  = threadIdx.x >> 6;
    const int lane = threadIdx.x & 63;
    const int bk   = blockIdx.x * 4 + wid;             // 0..8191

    const float* xr = ws + (size_t)bk * T_;
    const float* yr = ws + (size_t)(B_ * K_) * T_ + (size_t)bk * T_;

    float vx[16], vy[16];
    #pragma unroll
    for (int i = 0; i < 4; ++i) {
        float4 f = *(const float4*)(xr + lane * 16 + i * 4);
        vx[i * 4 + 0] = f.x; vx[i * 4 + 1] = f.y;
        vx[i * 4 + 2] = f.z; vx[i * 4 + 3] = f.w;
        float4 g = *(const float4*)(yr + lane * 16 + i * 4);
        vy[i * 4 + 0] = g.x; vy[i * 4 + 1] = g.y;
        vy[i * 4 + 2] = g.z; vy[i * 4 + 3] = g.w;
    }

    // direction bits per block size (e & k, k>=16 -> lane bit)
    const bool u16  = (lane & 1)  == 0;
    const bool u32  = (lane & 2)  == 0;
    const bool u64  = (lane & 4)  == 0;
    const bool u128 = (lane & 8)  == 0;
    const bool u256 = (lane & 16) == 0;
    const bool u512 = (lane & 32) == 0;

    pre8(vx); pre8(vy);

    // k=16
    intra4U(vx, u16); intra4U(vy, u16);
    // k=32
    { const bool a = ((lane & 1) == 0) == u32;
      crossU<1>(vx, a); crossU<1>(vy, a); }
    intra4U(vx, u32); intra4U(vy, u32);
    // k=64
    { const bool a = ((lane & 2) == 0) == u64;
      crossU<2>(vx, a); crossU<2>(vy, a);
      const bool b = ((lane & 1) == 0) == u64;
      crossU<1>(vx, b); crossU<1>(vy, b); }
    intra4U(vx, u64); intra4U(vy, u64);
    // k=128
    { const bool a = ((lane & 4) == 0) == u128;
      crossU<4>(vx, a); crossU<4>(vy, a);
      const bool b = ((lane & 2) == 0) == u128;
      crossU<2>(vx, b); crossU<2>(vy, b);
      const bool c = ((lane & 1) == 0) == u128;
      crossU<1>(vx, c); crossU<1>(vy, c); }
    intra4U(vx, u128); intra4U(vy, u128);
    // k=256
    { const bool a = ((lane & 8) == 0) == u256;
      crossU<8>(vx, a); crossU<8>(vy, a);
      const bool b = ((lane & 4) == 0) == u256;
      crossU<4>(vx, b); crossU<4>(vy, b);
      const bool c = ((lane & 2) == 0) == u256;
      crossU<2>(vx, c); crossU<2>(vy, c);
      const bool d = ((lane & 1) == 0) == u256;
      crossU<1>(vx, d); crossU<1>(vy, d); }
    intra4U(vx, u256); intra4U(vy, u256);
    // k=512
    { const bool a = ((lane & 16) == 0) == u512;
      crossU<16>(vx, a); crossU<16>(vy, a);
      const bool b = ((lane & 8) == 0) == u512;
      crossU<8>(vx, b); crossU<8>(vy, b);
      const bool c = ((lane & 4) == 0) == u512;
      crossU<4>(vx, c); crossU<4>(vy, c);
      const bool d = ((lane & 2) == 0) == u512;
      crossU<2>(vx, d); crossU<2>(vy, d);
      const bool e = ((lane & 1) == 0) == u512;
      crossU<1>(vx, e); crossU<1>(vy, e); }
    intra4U(vx, u512); intra4U(vy, u512);
    // k=1024 (up == true everywhere)
    { const bool a = (lane & 32) == 0;
      crossU<32>(vx, a); crossU<32>(vy, a);
      const bool b = (lane & 16) == 0;
      crossU<16>(vx, b); crossU<16>(vy, b);
      const bool c = (lane & 8) == 0;
      crossU<8>(vx, c); crossU<8>(vy, c);
      const bool d = (lane & 4) == 0;
      crossU<4>(vx, d); crossU<4>(vy, d);
      const bool e = (lane & 2) == 0;
      crossU<2>(vx, e); crossU<2>(vy, e);
      const bool f = (lane & 1) == 0;
      crossU<1>(vx, f); crossU<1>(vy, f); }
    intra4A(vx); intra4A(vy);

    float s = 0.0f;
    #pragma unroll
    for (int r = 0; r < 16; ++r) {
        float d = vx[r] - vy[r];
        s += d * d;
    }
    #pragma unroll
    for (int m = 1; m <= 32; m <<= 1) s += __shfl_xor(s, m);
    if (lane == 0) cost[bk] = s;
}

// ---------------------------------------------------------------------------
// Kernel 3: sw[b] = sanitize(sqrt(sum_k cost / (K*T)))
// ---------------------------------------------------------------------------
__global__ void finalize_kernel(const float* __restrict__ cost,
                                float* __restrict__ out) {
    const int b = threadIdx.x;
    if (b >= B_) return;
    float s = 0.0f;
    for (int k = 0; k < K_; ++k) s += cost[b * K_ + k];
    float sw = sqrtf(s * (1.0f / (float)(K_ * T_)));
    if (isnan(sw)) sw = 1e4f;
    else if (isinf(sw)) sw = sw > 0.0f ? 1e4f : 0.0f;
    out[b] = sw;
}

extern "C" void kernel_launch(void* const* d_in, const int* in_sizes, int n_in,
                              void* d_out, int out_size, void* d_ws, size_t ws_size,
                              hipStream_t stream) {
    const float* x    = (const float*)d_in[0];
    const float* y    = (const float*)d_in[1];
    const float* proj = (const float*)d_in[2];
    float* wsf = (float*)d_ws;
    unsigned short* pt = (unsigned short*)(wsf + (size_t)2 * B_ * K_ * T_);
    float* cost = (float*)(pt + (size_t)K_ * D_);
    float* out  = (float*)d_out;

    transpose_proj_kernel<<<(D_ * K_ + 255) / 256, 256, 0, stream>>>(proj, pt);
    proj_kernel<<<dim3(8, B_, 2), 256, 0, stream>>>(x, y, pt, wsf);
    sort_cost_kernel<<<(B_ * K_) / 4, 256, 0, stream>>>(wsf, cost);
    finalize_kernel<<<1, 64, 0, stream>>>(cost, out);
}

// Round 9
// 142.751 us; speedup vs baseline: 1.8489x; 1.0213x over previous
//
#include <hip/hip_runtime.h>
#include <hip/hip_bf16.h>

#define B_ 64
#define T_ 1024
#define D_ 256
#define K_ 128

typedef __attribute__((ext_vector_type(8))) short bf16x8;
typedef __attribute__((ext_vector_type(4))) float f32x4;

__device__ __forceinline__ float san(float v) {
    if (isnan(v)) return 0.0f;
    if (isinf(v)) return v > 0.0f ? 1e4f : -1e4f;
    return v;
}

__device__ __forceinline__ float4 san4(float4 f) {
    f.x = san(f.x); f.y = san(f.y); f.z = san(f.z); f.w = san(f.w);
    return f;
}

// RNE float->bf16 (inputs pre-sanitized: no NaN/Inf)
__device__ __forceinline__ unsigned int f2bf(float f) {
    unsigned int u = __builtin_bit_cast(unsigned int, f);
    u += 0x7fffu + ((u >> 16) & 1u);
    return u >> 16;
}

// ---------------------------------------------------------------------------
// Kernel 0: proj (D,K) fp32 -> projT (K,D) bf16  (tiny one-time transpose)
// ---------------------------------------------------------------------------
__global__ void transpose_proj_kernel(const float* __restrict__ proj,
                                      unsigned short* __restrict__ pt) {
    int e = blockIdx.x * 256 + threadIdx.x;       // 32768 elems
    if (e < D_ * K_) {
        int d = e >> 7, k = e & 127;
        pt[k * D_ + d] = (unsigned short)f2bf(proj[e]);
    }
}

// ---------------------------------------------------------------------------
// Kernel 1: fused sanitize + bf16 MFMA projection + deferred L2-normalize.
// v3: 512 threads (8 waves), tile 128t x 128k, wave = 16t x 128k.
// Global loads batched to registers (fbuf/ubuf) before processing -> MLP.
// __launch_bounds__(512,4): VGPR<=128, 2 blocks/CU = 16 waves/CU.
// LDS row-major [row][128 d] bf16, byte-swizzle ^((row&7)<<4)  (verified R4).
// Output layout: out[z][b][k][t]  fp32.
// ---------------------------------------------------------------------------
__global__ __launch_bounds__(512, 4)
void proj_kernel(const float* __restrict__ xin, const float* __restrict__ yin,
                 const unsigned short* __restrict__ pt, float* __restrict__ outp) {
    __shared__ short As[128 * 128];   // 32 KB
    __shared__ short Ps[128 * 128];   // 32 KB
    __shared__ float rnacc[128];

    const int tid  = threadIdx.x;
    const int lane = tid & 63;
    const int w    = tid >> 6;        // wave 0..7
    const int ttile = blockIdx.x;     // 0..7
    const int b     = blockIdx.y;     // 0..63
    const int z     = blockIdx.z;     // 0=x 1=y

    const float* src = (z == 0 ? xin : yin)
                     + (size_t)b * (T_ * D_) + (size_t)ttile * 128 * D_;

    f32x4 acc[8];
    #pragma unroll
    for (int j = 0; j < 8; ++j) acc[j] = (f32x4){0.f, 0.f, 0.f, 0.f};

    const int l15 = lane & 15;
    const int l4  = lane >> 4;

    for (int c = 0; c < 2; ++c) {
        // ---- issue ALL global loads for this chunk first (MLP) ----
        float4 fbuf[8];
        #pragma unroll
        for (int i = 0; i < 8; ++i) {
            int q  = i * 512 + tid;           // 4096 float4 slots
            int t  = q >> 5;
            int d4 = q & 31;
            fbuf[i] = *(const float4*)(src + t * D_ + c * 128 + d4 * 4);
        }
        uint4 ubuf[4];
        #pragma unroll
        for (int i = 0; i < 4; ++i) {
            int q  = i * 512 + tid;           // 2048 uint4 slots
            int k  = q >> 4;
            int d8 = q & 15;
            ubuf[i] = *(const uint4*)(pt + k * D_ + c * 128 + d8 * 8);
        }

        // ---- process A: sanitize, norm partials, bf16 pack, LDS ----
        #pragma unroll
        for (int i = 0; i < 8; ++i) {
            int q  = i * 512 + tid;
            int t  = q >> 5;
            int d4 = q & 31;
            float4 f = san4(fbuf[i]);
            float ssq = f.x * f.x + f.y * f.y + f.z * f.z + f.w * f.w;
            ssq += __shfl_xor(ssq, 1);
            ssq += __shfl_xor(ssq, 2);
            ssq += __shfl_xor(ssq, 4);
            ssq += __shfl_xor(ssq, 8);
            ssq += __shfl_xor(ssq, 16);
            if (d4 == 0) {
                if (c == 0) rnacc[t] = ssq;
                else        rnacc[t] += ssq;
            }
            uint2 p;
            p.x = f2bf(f.x) | (f2bf(f.y) << 16);
            p.y = f2bf(f.z) | (f2bf(f.w) << 16);
            int byteoff = (t * 256 + d4 * 8) ^ ((t & 7) << 4);
            *(uint2*)((char*)As + byteoff) = p;
        }
        // ---- process P ----
        #pragma unroll
        for (int i = 0; i < 4; ++i) {
            int q  = i * 512 + tid;
            int k  = q >> 4;
            int d8 = q & 15;
            int byteoff = (k * 256 + d8 * 16) ^ ((k & 7) << 4);
            *(uint4*)((char*)Ps + byteoff) = ubuf[i];
        }
        __syncthreads();

        // ---- MFMA: 4 k-steps of 32 d, wave owns 16 tokens ----
        #pragma unroll
        for (int ks = 0; ks < 4; ++ks) {
            const int kb = ks * 32;
            bf16x8 af;
            {
                int t = w * 16 + l15;
                int byteoff = (t * 256 + kb * 2 + l4 * 16) ^ ((t & 7) << 4);
                af = *(bf16x8*)((char*)As + byteoff);
            }
            bf16x8 pf[8];
            #pragma unroll
            for (int nt = 0; nt < 8; ++nt) {
                int k = nt * 16 + l15;
                int byteoff = (k * 256 + kb * 2 + l4 * 16) ^ ((k & 7) << 4);
                pf[nt] = *(bf16x8*)((char*)Ps + byteoff);
            }
            #pragma unroll
            for (int nt = 0; nt < 8; ++nt)
                acc[nt] = __builtin_amdgcn_mfma_f32_16x16x32_bf16(
                    af, pf[nt], acc[nt], 0, 0, 0);
        }
        __syncthreads();   // protect LDS before next chunk restage
    }

    // ---- finalize 1/norm ----
    if (tid < 128) rnacc[tid] = 1.0f / fmaxf(sqrtf(rnacc[tid]), 1e-6f);
    __syncthreads();

    // ---- epilogue: scale rows by 1/norm, store out[k][t] ----
    // C layout (verified R4): col = k = lane&15, row = t = (lane>>4)*4 + reg
    float* out = outp + (size_t)z * ((size_t)B_ * K_ * T_) + (size_t)b * (K_ * T_);
    const int tl = w * 16 + l4 * 4;              // local token base
    const int tg = ttile * 128 + tl;             // global t base
    float r0 = rnacc[tl + 0], r1 = rnacc[tl + 1];
    float r2 = rnacc[tl + 2], r3 = rnacc[tl + 3];
    #pragma unroll
    for (int nt = 0; nt < 8; ++nt) {
        int k = nt * 16 + l15;
        float4 v;
        v.x = acc[nt][0] * r0;
        v.y = acc[nt][1] * r1;
        v.z = acc[nt][2] * r2;
        v.w = acc[nt][3] * r3;
        *(float4*)(out + (size_t)k * T_ + tg) = v;
    }
}

// ---------------------------------------------------------------------------
// Kernel 2: per-wave register bitonic sort, FULLY STATIC network.
// (unchanged from R8 — sort dropped 102 -> ~50 us)
// ---------------------------------------------------------------------------
#define CE_A(a, b) { float _lo = fminf(a, b), _hi = fmaxf(a, b); a = _lo; b = _hi; }
#define CE_D(a, b) { float _lo = fminf(a, b), _hi = fmaxf(a, b); a = _hi; b = _lo; }

__device__ __forceinline__ void pre8(float v[16]) {
    CE_A(v[0], v[1]);  CE_D(v[2], v[3]);  CE_A(v[4], v[5]);  CE_D(v[6], v[7]);
    CE_A(v[8], v[9]);  CE_D(v[10], v[11]); CE_A(v[12], v[13]); CE_D(v[14], v[15]);
    CE_A(v[0], v[2]);  CE_A(v[1], v[3]);  CE_D(v[4], v[6]);  CE_D(v[5], v[7]);
    CE_A(v[8], v[10]); CE_A(v[9], v[11]); CE_D(v[12], v[14]); CE_D(v[13], v[15]);
    CE_A(v[0], v[1]);  CE_A(v[2], v[3]);  CE_D(v[4], v[5]);  CE_D(v[6], v[7]);
    CE_A(v[8], v[9]);  CE_A(v[10], v[11]); CE_D(v[12], v[13]); CE_D(v[14], v[15]);
    CE_A(v[0], v[4]);  CE_A(v[1], v[5]);  CE_A(v[2], v[6]);  CE_A(v[3], v[7]);
    CE_D(v[8], v[12]); CE_D(v[9], v[13]); CE_D(v[10], v[14]); CE_D(v[11], v[15]);
    CE_A(v[0], v[2]);  CE_A(v[1], v[3]);  CE_A(v[4], v[6]);  CE_A(v[5], v[7]);
    CE_D(v[8], v[10]); CE_D(v[9], v[11]); CE_D(v[12], v[14]); CE_D(v[13], v[15]);
    CE_A(v[0], v[1]);  CE_A(v[2], v[3]);  CE_A(v[4], v[5]);  CE_A(v[6], v[7]);
    CE_D(v[8], v[9]);  CE_D(v[10], v[11]); CE_D(v[12], v[13]); CE_D(v[14], v[15]);
}

template <int J>
__device__ __forceinline__ void intraU(float v[16], bool up) {
    #pragma unroll
    for (int r = 0; r < 16; ++r) {
        if ((r & J) == 0) {
            const int p = r | J;
            float lo = fminf(v[r], v[p]), hi = fmaxf(v[r], v[p]);
            v[r] = up ? lo : hi;
            v[p] = up ? hi : lo;
        }
    }
}

__device__ __forceinline__ void intra4U(float v[16], bool up) {
    intraU<8>(v, up); intraU<4>(v, up); intraU<2>(v, up); intraU<1>(v, up);
}

__device__ __forceinline__ void intra4A(float v[16]) {
    CE_A(v[0], v[8]);  CE_A(v[1], v[9]);  CE_A(v[2], v[10]); CE_A(v[3], v[11]);
    CE_A(v[4], v[12]); CE_A(v[5], v[13]); CE_A(v[6], v[14]); CE_A(v[7], v[15]);
    CE_A(v[0], v[4]);  CE_A(v[1], v[5]);  CE_A(v[2], v[6]);  CE_A(v[3], v[7]);
    CE_A(v[8], v[12]); CE_A(v[9], v[13]); CE_A(v[10], v[14]); CE_A(v[11], v[15]);
    CE_A(v[0], v[2]);  CE_A(v[1], v[3]);  CE_A(v[4], v[6]);  CE_A(v[5], v[7]);
    CE_A(v[8], v[10]); CE_A(v[9], v[11]); CE_A(v[12], v[14]); CE_A(v[13], v[15]);
    CE_A(v[0], v[1]);  CE_A(v[2], v[3]);  CE_A(v[4], v[5]);  CE_A(v[6], v[7]);
    CE_A(v[8], v[9]);  CE_A(v[10], v[11]); CE_A(v[12], v[13]); CE_A(v[14], v[15]);
}

template <int M>
__device__ __forceinline__ void crossU(float v[16], bool keepmin) {
    #pragma unroll
    for (int r = 0; r < 16; ++r) {
        float o  = __shfl_xor(v[r], M);
        float mn = fminf(v[r], o), mx = fmaxf(v[r], o);
        v[r] = keepmin ? mn : mx;
    }
}

__global__ __launch_bounds__(256)
void sort_cost_kernel(const float* __restrict__ ws, float* __restrict__ cost) {
    const int wid  = threadIdx.x >> 6;
    const int lane = threadIdx.x & 63;
    const int bk   = blockIdx.x * 4 + wid;             // 0..8191

    const float* xr = ws + (size_t)bk * T_;
    const float* yr = ws + (size_t)(B_ * K_) * T_ + (size_t)bk * T_;

    float vx[16], vy[16];
    #pragma unroll
    for (int i = 0; i < 4; ++i) {
        float4 f = *(const float4*)(xr + lane * 16 + i * 4);
        vx[i * 4 + 0] = f.x; vx[i * 4 + 1] = f.y;
        vx[i * 4 + 2] = f.z; vx[i * 4 + 3] = f.w;
        float4 g = *(const float4*)(yr + lane * 16 + i * 4);
        vy[i * 4 + 0] = g.x; vy[i * 4 + 1] = g.y;
        vy[i * 4 + 2] = g.z; vy[i * 4 + 3] = g.w;
    }

    const bool u16  = (lane & 1)  == 0;
    const bool u32  = (lane & 2)  == 0;
    const bool u64  = (lane & 4)  == 0;
    const bool u128 = (lane & 8)  == 0;
    const bool u256 = (lane & 16) == 0;
    const bool u512 = (lane & 32) == 0;

    pre8(vx); pre8(vy);

    intra4U(vx, u16); intra4U(vy, u16);
    { const bool a = ((lane & 1) == 0) == u32;
      crossU<1>(vx, a); crossU<1>(vy, a); }
    intra4U(vx, u32); intra4U(vy, u32);
    { const bool a = ((lane & 2) == 0) == u64;
      crossU<2>(vx, a); crossU<2>(vy, a);
      const bool b = ((lane & 1) == 0) == u64;
      crossU<1>(vx, b); crossU<1>(vy, b); }
    intra4U(vx, u64); intra4U(vy, u64);
    { const bool a = ((lane & 4) == 0) == u128;
      crossU<4>(vx, a); crossU<4>(vy, a);
      const bool b = ((lane & 2) == 0) == u128;
      crossU<2>(vx, b); crossU<2>(vy, b);
      const bool c = ((lane & 1) == 0) == u128;
      crossU<1>(vx, c); crossU<1>(vy, c); }
    intra4U(vx, u128); intra4U(vy, u128);
    { const bool a = ((lane & 8) == 0) == u256;
      crossU<8>(vx, a); crossU<8>(vy, a);
      const bool b = ((lane & 4) == 0) == u256;
      crossU<4>(vx, b); crossU<4>(vy, b);
      const bool c = ((lane & 2) == 0) == u256;
      crossU<2>(vx, c); crossU<2>(vy, c);
      const bool d = ((lane & 1) == 0) == u256;
      crossU<1>(vx, d); crossU<1>(vy, d); }
    intra4U(vx, u256); intra4U(vy, u256);
    { const bool a = ((lane & 16) == 0) == u512;
      crossU<16>(vx, a); crossU<16>(vy, a);
      const bool b = ((lane & 8) == 0) == u512;
      crossU<8>(vx, b); crossU<8>(vy, b);
      const bool c = ((lane & 4) == 0) == u512;
      crossU<4>(vx, c); crossU<4>(vy, c);
      const bool d = ((lane & 2) == 0) == u512;
      crossU<2>(vx, d); crossU<2>(vy, d);
      const bool e = ((lane & 1) == 0) == u512;
      crossU<1>(vx, e); crossU<1>(vy, e); }
    intra4U(vx, u512); intra4U(vy, u512);
    { const bool a = (lane & 32) == 0;
      crossU<32>(vx, a); crossU<32>(vy, a);
      const bool b = (lane & 16) == 0;
      crossU<16>(vx, b); crossU<16>(vy, b);
      const bool c = (lane & 8) == 0;
      crossU<8>(vx, c); crossU<8>(vy, c);
      const bool d = (lane & 4) == 0;
      crossU<4>(vx, d); crossU<4>(vy, d);
      const bool e = (lane & 2) == 0;
      crossU<2>(vx, e); crossU<2>(vy, e);
      const bool f = (lane & 1) == 0;
      crossU<1>(vx, f); crossU<1>(vy, f); }
    intra4A(vx); intra4A(vy);

    float s = 0.0f;
    #pragma unroll
    for (int r = 0; r < 16; ++r) {
        float d = vx[r] - vy[r];
        s += d * d;
    }
    #pragma unroll
    for (int m = 1; m <= 32; m <<= 1) s += __shfl_xor(s, m);
    if (lane == 0) cost[bk] = s;
}

// ---------------------------------------------------------------------------
// Kernel 3: sw[b] = sanitize(sqrt(sum_k cost / (K*T)))
// ---------------------------------------------------------------------------
__global__ void finalize_kernel(const float* __restrict__ cost,
                                float* __restrict__ out) {
    const int b = threadIdx.x;
    if (b >= B_) return;
    float s = 0.0f;
    for (int k = 0; k < K_; ++k) s += cost[b * K_ + k];
    float sw = sqrtf(s * (1.0f / (float)(K_ * T_)));
    if (isnan(sw)) sw = 1e4f;
    else if (isinf(sw)) sw = sw > 0.0f ? 1e4f : 0.0f;
    out[b] = sw;
}

extern "C" void kernel_launch(void* const* d_in, const int* in_sizes, int n_in,
                              void* d_out, int out_size, void* d_ws, size_t ws_size,
                              hipStream_t stream) {
    const float* x    = (const float*)d_in[0];
    const float* y    = (const float*)d_in[1];
    const float* proj = (const float*)d_in[2];
    float* wsf = (float*)d_ws;
    unsigned short* pt = (unsigned short*)(wsf + (size_t)2 * B_ * K_ * T_);
    float* cost = (float*)(pt + (size_t)K_ * D_);
    float* out  = (float*)d_out;

    transpose_proj_kernel<<<(D_ * K_ + 255) / 256, 256, 0, stream>>>(proj, pt);
    proj_kernel<<<dim3(8, B_, 2), 512, 0, stream>>>(x, y, pt, wsf);
    sort_cost_kernel<<<(B_ * K_) / 4, 256, 0, stream>>>(wsf, cost);
    finalize_kernel<<<1, 64, 0, stream>>>(cost, out);
}

// Round 11
// 120.276 us; speedup vs baseline: 2.1944x; 1.1869x over previous
//
#include <hip/hip_runtime.h>
#include <hip/hip_bf16.h>

#define B_ 64
#define T_ 1024
#define D_ 256
#define K_ 128

typedef __attribute__((ext_vector_type(8))) short bf16x8;
typedef __attribute__((ext_vector_type(4))) float f32x4;
typedef __fp16 h2 __attribute__((ext_vector_type(2)));
typedef unsigned int u32;

__device__ __forceinline__ float san(float v) {
    if (isnan(v)) return 0.0f;
    if (isinf(v)) return v > 0.0f ? 1e4f : -1e4f;
    return v;
}

__device__ __forceinline__ float4 san4(float4 f) {
    f.x = san(f.x); f.y = san(f.y); f.z = san(f.z); f.w = san(f.w);
    return f;
}

// RNE float->bf16 (inputs pre-sanitized: no NaN/Inf)
__device__ __forceinline__ u32 f2bf(float f) {
    u32 u = __builtin_bit_cast(u32, f);
    u += 0x7fffu + ((u >> 16) & 1u);
    return u >> 16;
}

// ---------------------------------------------------------------------------
// Kernel 0: proj (D,K) fp32 -> projT (K,D) bf16  (tiny one-time transpose)
// ---------------------------------------------------------------------------
__global__ void transpose_proj_kernel(const float* __restrict__ proj,
                                      unsigned short* __restrict__ pt) {
    int e = blockIdx.x * 256 + threadIdx.x;       // 32768 elems
    if (e < D_ * K_) {
        int d = e >> 7, k = e & 127;
        pt[k * D_ + d] = (unsigned short)f2bf(proj[e]);
    }
}

// ---------------------------------------------------------------------------
// Kernel 1: fused sanitize + bf16 MFMA projection + deferred L2-normalize.
// (R9 structure: 512 thr / 8 waves, batched loads; epilogue stores fp16
// packed keys via v_cvt_pkrtz -> halves write traffic and feeds packed sort.)
// Output layout: out[z][b][k][t]  fp16.
// ---------------------------------------------------------------------------
__global__ __launch_bounds__(512, 4)
void proj_kernel(const float* __restrict__ xin, const float* __restrict__ yin,
                 const unsigned short* __restrict__ pt,
                 unsigned short* __restrict__ outh) {
    __shared__ short As[128 * 128];   // 32 KB
    __shared__ short Ps[128 * 128];   // 32 KB
    __shared__ float rnacc[128];

    const int tid  = threadIdx.x;
    const int lane = tid & 63;
    const int w    = tid >> 6;        // wave 0..7
    const int ttile = blockIdx.x;     // 0..7
    const int b     = blockIdx.y;     // 0..63
    const int z     = blockIdx.z;     // 0=x 1=y

    const float* src = (z == 0 ? xin : yin)
                     + (size_t)b * (T_ * D_) + (size_t)ttile * 128 * D_;

    f32x4 acc[8];
    #pragma unroll
    for (int j = 0; j < 8; ++j) acc[j] = (f32x4){0.f, 0.f, 0.f, 0.f};

    const int l15 = lane & 15;
    const int l4  = lane >> 4;

    for (int c = 0; c < 2; ++c) {
        // ---- issue ALL global loads for this chunk first (MLP) ----
        float4 fbuf[8];
        #pragma unroll
        for (int i = 0; i < 8; ++i) {
            int q  = i * 512 + tid;
            int t  = q >> 5;
            int d4 = q & 31;
            fbuf[i] = *(const float4*)(src + t * D_ + c * 128 + d4 * 4);
        }
        uint4 ubuf[4];
        #pragma unroll
        for (int i = 0; i < 4; ++i) {
            int q  = i * 512 + tid;
            int k  = q >> 4;
            int d8 = q & 15;
            ubuf[i] = *(const uint4*)(pt + k * D_ + c * 128 + d8 * 8);
        }

        // ---- process A: sanitize, norm partials, bf16 pack, LDS ----
        #pragma unroll
        for (int i = 0; i < 8; ++i) {
            int q  = i * 512 + tid;
            int t  = q >> 5;
            int d4 = q & 31;
            float4 f = san4(fbuf[i]);
            float ssq = f.x * f.x + f.y * f.y + f.z * f.z + f.w * f.w;
            ssq += __shfl_xor(ssq, 1);
            ssq += __shfl_xor(ssq, 2);
            ssq += __shfl_xor(ssq, 4);
            ssq += __shfl_xor(ssq, 8);
            ssq += __shfl_xor(ssq, 16);
            if (d4 == 0) {
                if (c == 0) rnacc[t] = ssq;
                else        rnacc[t] += ssq;
            }
            uint2 p;
            p.x = f2bf(f.x) | (f2bf(f.y) << 16);
            p.y = f2bf(f.z) | (f2bf(f.w) << 16);
            int byteoff = (t * 256 + d4 * 8) ^ ((t & 7) << 4);
            *(uint2*)((char*)As + byteoff) = p;
        }
        // ---- process P ----
        #pragma unroll
        for (int i = 0; i < 4; ++i) {
            int q  = i * 512 + tid;
            int k  = q >> 4;
            int d8 = q & 15;
            int byteoff = (k * 256 + d8 * 16) ^ ((k & 7) << 4);
            *(uint4*)((char*)Ps + byteoff) = ubuf[i];
        }
        __syncthreads();

        // ---- MFMA: 4 k-steps of 32 d, wave owns 16 tokens ----
        #pragma unroll
        for (int ks = 0; ks < 4; ++ks) {
            const int kb = ks * 32;
            bf16x8 af;
            {
                int t = w * 16 + l15;
                int byteoff = (t * 256 + kb * 2 + l4 * 16) ^ ((t & 7) << 4);
                af = *(bf16x8*)((char*)As + byteoff);
            }
            bf16x8 pf[8];
            #pragma unroll
            for (int nt = 0; nt < 8; ++nt) {
                int k = nt * 16 + l15;
                int byteoff = (k * 256 + kb * 2 + l4 * 16) ^ ((k & 7) << 4);
                pf[nt] = *(bf16x8*)((char*)Ps + byteoff);
            }
            #pragma unroll
            for (int nt = 0; nt < 8; ++nt)
                acc[nt] = __builtin_amdgcn_mfma_f32_16x16x32_bf16(
                    af, pf[nt], acc[nt], 0, 0, 0);
        }
        __syncthreads();
    }

    // ---- finalize 1/norm ----
    if (tid < 128) rnacc[tid] = 1.0f / fmaxf(sqrtf(rnacc[tid]), 1e-6f);
    __syncthreads();

    // ---- epilogue: scale rows by 1/norm, store fp16 out[k][t] ----
    // C layout (verified R4): col = k = lane&15, row = t = (lane>>4)*4 + reg
    unsigned short* out = outh + (size_t)z * ((size_t)B_ * K_ * T_)
                               + (size_t)b * (K_ * T_);
    const int tl = w * 16 + l4 * 4;
    const int tg = ttile * 128 + tl;
    float r0 = rnacc[tl + 0], r1 = rnacc[tl + 1];
    float r2 = rnacc[tl + 2], r3 = rnacc[tl + 3];
    #pragma unroll
    for (int nt = 0; nt < 8; ++nt) {
        int k = nt * 16 + l15;
        auto p0 = __builtin_amdgcn_cvt_pkrtz(acc[nt][0] * r0, acc[nt][1] * r1);
        auto p1 = __builtin_amdgcn_cvt_pkrtz(acc[nt][2] * r2, acc[nt][3] * r3);
        uint2 u;
        u.x = __builtin_bit_cast(u32, p0);
        u.y = __builtin_bit_cast(u32, p1);
        *(uint2*)(out + (size_t)k * T_ + tg) = u;
    }
}

// ---------------------------------------------------------------------------
// Kernel 2: per-wave PACKED-fp16 register bitonic sort.
// Element e = lane*16 + idx; idx = reg*2 + half (8 x u32 = 16 fp16 per lane).
// v_pk_min/max_f16 (via __builtin_elementwise_*) = 2 elems/op; shuffles move
// 2 elems/op. Same network/directions as the verified R8 scalar version.
// Data is sanitized (no NaN/Inf), so min/max NaN semantics are irrelevant.
// ---------------------------------------------------------------------------
__device__ __forceinline__ u32 hmin2u(u32 a, u32 b) {
    h2 r = __builtin_elementwise_min(__builtin_bit_cast(h2, a),
                                     __builtin_bit_cast(h2, b));
    return __builtin_bit_cast(u32, r);
}
__device__ __forceinline__ u32 hmax2u(u32 a, u32 b) {
    h2 r = __builtin_elementwise_max(__builtin_bit_cast(h2, a),
                                     __builtin_bit_cast(h2, b));
    return __builtin_bit_cast(u32, r);
}
__device__ __forceinline__ u32 swap16(u32 x) {
    return __builtin_amdgcn_alignbit(x, x, 16);
}
// {lo: lo_src.lo, hi: hi_src.hi}
__device__ __forceinline__ u32 blendlh(u32 hi_src, u32 lo_src) {
    return __builtin_amdgcn_perm(hi_src, lo_src, 0x07060100);
}

// within-reg (j=1) CEs
__device__ __forceinline__ void ce1A(u32& h) {            // ascending
    u32 s = swap16(h), mn = hmin2u(h, s), mx = hmax2u(h, s);
    h = blendlh(mx, mn);                                   // {min, max}
}
__device__ __forceinline__ void ce1D(u32& h) {            // descending
    u32 s = swap16(h), mn = hmin2u(h, s), mx = hmax2u(h, s);
    h = blendlh(mn, mx);                                   // {max, min}
}
__device__ __forceinline__ void ce1U(u32& h, bool up) {   // runtime dir
    u32 s = swap16(h), mn = hmin2u(h, s), mx = hmax2u(h, s);
    u32 A = blendlh(mx, mn), B = blendlh(mn, mx);
    h = up ? A : B;
}

// cross-reg CEs (j = 2,4,8): a = lower-index side
__device__ __forceinline__ void cePA(u32& a, u32& b) {
    u32 mn = hmin2u(a, b), mx = hmax2u(a, b); a = mn; b = mx;
}
__device__ __forceinline__ void cePD(u32& a, u32& b) {
    u32 mn = hmin2u(a, b), mx = hmax2u(a, b); a = mx; b = mn;
}
__device__ __forceinline__ void cePU(u32& a, u32& b, bool up) {
    u32 mn = hmin2u(a, b), mx = hmax2u(a, b);
    a = up ? mn : mx; b = up ? mx : mn;
}

// cross-lane layer, immediate mask M (lane mask), keepmin per lane
template <int M>
__device__ __forceinline__ void crossP(u32 h[8], bool keep) {
    #pragma unroll
    for (int r = 0; r < 8; ++r) {
        u32 o  = (u32)__shfl_xor((int)h[r], M);
        u32 mn = hmin2u(h[r], o), mx = hmax2u(h[r], o);
        h[r] = keep ? mn : mx;
    }
}

// stages k=2,4,8 (static directions by reg/half bits)
__device__ __forceinline__ void pre8P(u32 h[8]) {
    // k=2, j=1: dir by idx bit1 (reg bit0)
    ce1A(h[0]); ce1D(h[1]); ce1A(h[2]); ce1D(h[3]);
    ce1A(h[4]); ce1D(h[5]); ce1A(h[6]); ce1D(h[7]);
    // k=4, j=2: pairs (0,1)(2,3)..., dir by reg bit1
    cePA(h[0], h[1]); cePD(h[2], h[3]); cePA(h[4], h[5]); cePD(h[6], h[7]);
    // k=4, j=1
    ce1A(h[0]); ce1A(h[1]); ce1D(h[2]); ce1D(h[3]);
    ce1A(h[4]); ce1A(h[5]); ce1D(h[6]); ce1D(h[7]);
    // k=8, j=4: pairs (0,2)(1,3)(4,6)(5,7), dir by reg bit2
    cePA(h[0], h[2]); cePA(h[1], h[3]); cePD(h[4], h[6]); cePD(h[5], h[7]);
    // k=8, j=2
    cePA(h[0], h[1]); cePA(h[2], h[3]); cePD(h[4], h[5]); cePD(h[6], h[7]);
    // k=8, j=1
    ce1A(h[0]); ce1A(h[1]); ce1A(h[2]); ce1A(h[3]);
    ce1D(h[4]); ce1D(h[5]); ce1D(h[6]); ce1D(h[7]);
}

// runtime-direction intra block (j=8,4,2,1)
__device__ __forceinline__ void intraPU(u32 h[8], bool up) {
    cePU(h[0], h[4], up); cePU(h[1], h[5], up);
    cePU(h[2], h[6], up); cePU(h[3], h[7], up);
    cePU(h[0], h[2], up); cePU(h[1], h[3], up);
    cePU(h[4], h[6], up); cePU(h[5], h[7], up);
    cePU(h[0], h[1], up); cePU(h[2], h[3], up);
    cePU(h[4], h[5], up); cePU(h[6], h[7], up);
    ce1U(h[0], up); ce1U(h[1], up); ce1U(h[2], up); ce1U(h[3], up);
    ce1U(h[4], up); ce1U(h[5], up); ce1U(h[6], up); ce1U(h[7], up);
}

// final all-ascending intra block
__device__ __forceinline__ void intraPA(u32 h[8]) {
    cePA(h[0], h[4]); cePA(h[1], h[5]); cePA(h[2], h[6]); cePA(h[3], h[7]);
    cePA(h[0], h[2]); cePA(h[1], h[3]); cePA(h[4], h[6]); cePA(h[5], h[7]);
    cePA(h[0], h[1]); cePA(h[2], h[3]); cePA(h[4], h[5]); cePA(h[6], h[7]);
    ce1A(h[0]); ce1A(h[1]); ce1A(h[2]); ce1A(h[3]);
    ce1A(h[4]); ce1A(h[5]); ce1A(h[6]); ce1A(h[7]);
}

__global__ __launch_bounds__(256)
void sort_cost_kernel(const unsigned short* __restrict__ wsh,
                      float* __restrict__ cost) {
    const int wid  = threadIdx.x >> 6;
    const int lane = threadIdx.x & 63;
    const int bk   = blockIdx.x * 4 + wid;             // 0..8191

    const unsigned short* xr = wsh + (size_t)bk * T_;
    const unsigned short* yr = wsh + (size_t)(B_ * K_) * T_ + (size_t)bk * T_;

    u32 hx[8], hy[8];
    {
        const uint4* px = (const uint4*)(xr + lane * 16);
        uint4 a = px[0], b = px[1];
        hx[0] = a.x; hx[1] = a.y; hx[2] = a.z; hx[3] = a.w;
        hx[4] = b.x; hx[5] = b.y; hx[6] = b.z; hx[7] = b.w;
        const uint4* py = (const uint4*)(yr + lane * 16);
        uint4 c = py[0], d = py[1];
        hy[0] = c.x; hy[1] = c.y; hy[2] = c.z; hy[3] = c.w;
        hy[4] = d.x; hy[5] = d.y; hy[6] = d.z; hy[7] = d.w;
    }

    // direction bits per block size (e & k, k>=16 -> lane bit)
    const bool b16  = (lane & 1)  == 0;
    const bool b32  = (lane & 2)  == 0;
    const bool b64  = (lane & 4)  == 0;
    const bool b128 = (lane & 8)  == 0;
    const bool b256 = (lane & 16) == 0;
    const bool b512 = (lane & 32) == 0;

    pre8P(hx); pre8P(hy);

    // k=16
    intraPU(hx, b16); intraPU(hy, b16);
    // k=32
    { const bool a = ((lane & 1) == 0) == b32;
      crossP<1>(hx, a); crossP<1>(hy, a); }
    intraPU(hx, b32); intraPU(hy, b32);
    // k=64
    { const bool a = ((lane & 2) == 0) == b64;
      crossP<2>(hx, a); crossP<2>(hy, a);
      const bool b = ((lane & 1) == 0) == b64;
      crossP<1>(hx, b); crossP<1>(hy, b); }
    intraPU(hx, b64); intraPU(hy, b64);
    // k=128
    { const bool a = ((lane & 4) == 0) == b128;
      crossP<4>(hx, a); crossP<4>(hy, a);
      const bool b = ((lane & 2) == 0) == b128;
      crossP<2>(hx, b); crossP<2>(hy, b);
      const bool c = ((lane & 1) == 0) == b128;
      crossP<1>(hx, c); crossP<1>(hy, c); }
    intraPU(hx, b128); intraPU(hy, b128);
    // k=256
    { const bool a = ((lane & 8) == 0) == b256;
      crossP<8>(hx, a); crossP<8>(hy, a);
      const bool b = ((lane & 4) == 0) == b256;
      crossP<4>(hx, b); crossP<4>(hy, b);
      const bool c = ((lane & 2) == 0) == b256;
      crossP<2>(hx, c); crossP<2>(hy, c);
      const bool d = ((lane & 1) == 0) == b256;
      crossP<1>(hx, d); crossP<1>(hy, d); }
    intraPU(hx, b256); intraPU(hy, b256);
    // k=512
    { const bool a = ((lane & 16) == 0) == b512;
      crossP<16>(hx, a); crossP<16>(hy, a);
      const bool b = ((lane & 8) == 0) == b512;
      crossP<8>(hx, b); crossP<8>(hy, b);
      const bool c = ((lane & 4) == 0) == b512;
      crossP<4>(hx, c); crossP<4>(hy, c);
      const bool d = ((lane & 2) == 0) == b512;
      crossP<2>(hx, d); crossP<2>(hy, d);
      const bool e = ((lane & 1) == 0) == b512;
      crossP<1>(hx, e); crossP<1>(hy, e); }
    intraPU(hx, b512); intraPU(hy, b512);
    // k=1024 (ascending everywhere)
    { const bool a = (lane & 32) == 0;
      crossP<32>(hx, a); crossP<32>(hy, a);
      const bool b = (lane & 16) == 0;
      crossP<16>(hx, b); crossP<16>(hy, b);
      const bool c = (lane & 8) == 0;
      crossP<8>(hx, c); crossP<8>(hy, c);
      const bool d = (lane & 4) == 0;
      crossP<4>(hx, d); crossP<4>(hy, d);
      const bool e = (lane & 2) == 0;
      crossP<2>(hx, e); crossP<2>(hy, e);
      const bool f = (lane & 1) == 0;
      crossP<1>(hx, f); crossP<1>(hy, f); }
    intraPA(hx); intraPA(hy);

    // cost: sum of squared diffs of position-matched sorted values
    float s = 0.0f;
    #pragma unroll
    for (int r = 0; r < 8; ++r) {
        h2 vx = __builtin_bit_cast(h2, hx[r]);
        h2 vy = __builtin_bit_cast(h2, hy[r]);
        float d0 = (float)vx[0] - (float)vy[0];
        float d1 = (float)vx[1] - (float)vy[1];
        s += d0 * d0 + d1 * d1;
    }
    #pragma unroll
    for (int m = 1; m <= 32; m <<= 1) s += __shfl_xor(s, m);
    if (lane == 0) cost[bk] = s;
}

// ---------------------------------------------------------------------------
// Kernel 3: sw[b] = sanitize(sqrt(sum_k cost / (K*T)))
// ---------------------------------------------------------------------------
__global__ void finalize_kernel(const float* __restrict__ cost,
                                float* __restrict__ out) {
    const int b = threadIdx.x;
    if (b >= B_) return;
    float s = 0.0f;
    for (int k = 0; k < K_; ++k) s += cost[b * K_ + k];
    float sw = sqrtf(s * (1.0f / (float)(K_ * T_)));
    if (isnan(sw)) sw = 1e4f;
    else if (isinf(sw)) sw = sw > 0.0f ? 1e4f : 0.0f;
    out[b] = sw;
}

extern "C" void kernel_launch(void* const* d_in, const int* in_sizes, int n_in,
                              void* d_out, int out_size, void* d_ws, size_t ws_size,
                              hipStream_t stream) {
    const float* x    = (const float*)d_in[0];
    const float* y    = (const float*)d_in[1];
    const float* proj = (const float*)d_in[2];
    // ws layout: [xp|yp] fp16 (32 MB), projT bf16 (64 KB), cost fp32 (32 KB)
    unsigned short* wsh = (unsigned short*)d_ws;
    unsigned short* pt  = wsh + (size_t)2 * B_ * K_ * T_;
    float* cost = (float*)(pt + (size_t)K_ * D_);
    float* out  = (float*)d_out;

    transpose_proj_kernel<<<(D_ * K_ + 255) / 256, 256, 0, stream>>>(proj, pt);
    proj_kernel<<<dim3(8, B_, 2), 512, 0, stream>>>(x, y, pt, wsh);
    sort_cost_kernel<<<(B_ * K_) / 4, 256, 0, stream>>>(wsh, cost);
    finalize_kernel<<<1, 64, 0, stream>>>(cost, out);
}

// Round 13
// 105.152 us; speedup vs baseline: 2.5100x; 1.1438x over previous
//
#include <hip/hip_runtime.h>
#include <hip/hip_bf16.h>

#define B_ 64
#define T_ 1024
#define D_ 256
#define K_ 128

typedef __attribute__((ext_vector_type(8))) short bf16x8;
typedef __attribute__((ext_vector_type(4))) float f32x4;
typedef __fp16 h2 __attribute__((ext_vector_type(2)));
typedef unsigned int u32;

__device__ __forceinline__ float san(float v) {
    if (isnan(v)) return 0.0f;
    if (isinf(v)) return v > 0.0f ? 1e4f : -1e4f;
    return v;
}

__device__ __forceinline__ float4 san4(float4 f) {
    f.x = san(f.x); f.y = san(f.y); f.z = san(f.z); f.w = san(f.w);
    return f;
}

// RNE float->bf16 (inputs pre-sanitized: no NaN/Inf)
__device__ __forceinline__ u32 f2bf(float f) {
    u32 u = __builtin_bit_cast(u32, f);
    u += 0x7fffu + ((u >> 16) & 1u);
    return u >> 16;
}

// ---------------------------------------------------------------------------
// Kernel 0: proj (D,K) fp32 -> projT (K,D) bf16  (tiny one-time transpose)
// ---------------------------------------------------------------------------
__global__ void transpose_proj_kernel(const float* __restrict__ proj,
                                      unsigned short* __restrict__ pt) {
    int e = blockIdx.x * 256 + threadIdx.x;       // 32768 elems
    if (e < D_ * K_) {
        int d = e >> 7, k = e & 127;
        pt[k * D_ + d] = (unsigned short)f2bf(proj[e]);
    }
}

// ---------------------------------------------------------------------------
// Kernel 1: fused sanitize + bf16 MFMA projection + deferred L2-normalize.
// R12: (a) row-local staging: thread owns 32 d of ONE token -> ssq is
// register-local, only 2 shfl_xor per chunk (was 5 per float4-group).
// (b) epilogue transposes C through LDS (reusing As) -> fully coalesced
// 64B-line fp16 global writes (kills read-modify-write traffic).
// Output layout: out[z][b][k][t]  fp16.
// ---------------------------------------------------------------------------
__global__ __launch_bounds__(512, 4)
void proj_kernel(const float* __restrict__ xin, const float* __restrict__ yin,
                 const unsigned short* __restrict__ pt,
                 unsigned short* __restrict__ outh) {
    __shared__ short As[128 * 128];   // 32 KB: A tile, then reused for C
    __shared__ short Ps[128 * 128];   // 32 KB
    __shared__ float rnacc[128];

    const int tid  = threadIdx.x;
    const int lane = tid & 63;
    const int w    = tid >> 6;        // wave 0..7
    const int ttile = blockIdx.x;     // 0..7
    const int b     = blockIdx.y;     // 0..63
    const int z     = blockIdx.z;     // 0=x 1=y

    const float* src = (z == 0 ? xin : yin)
                     + (size_t)b * (T_ * D_) + (size_t)ttile * 128 * D_;

    f32x4 acc[8];
    #pragma unroll
    for (int j = 0; j < 8; ++j) acc[j] = (f32x4){0.f, 0.f, 0.f, 0.f};

    const int l15 = lane & 15;
    const int l4  = lane >> 4;
    const int row  = tid >> 2;        // token row 0..127
    const int part = tid & 3;         // d-quarter (8 float4 each)

    for (int c = 0; c < 2; ++c) {
        // ---- issue ALL global loads (8 indep float4 per thread, one row) ----
        const float4* rp = (const float4*)(src + row * D_ + c * 128 + part * 32);
        float4 fbuf[8];
        #pragma unroll
        for (int i = 0; i < 8; ++i) fbuf[i] = rp[i];
        uint4 ubuf[4];
        #pragma unroll
        for (int i = 0; i < 4; ++i) {
            int q  = i * 512 + tid;
            int k  = q >> 4;
            int d8 = q & 15;
            ubuf[i] = *(const uint4*)(pt + k * D_ + c * 128 + d8 * 8);
        }

        // ---- process A: sanitize, local ssq, bf16 pack, LDS ----
        float ssq = 0.0f;
        #pragma unroll
        for (int i = 0; i < 8; ++i) {
            float4 f = san4(fbuf[i]);
            ssq += f.x * f.x + f.y * f.y + f.z * f.z + f.w * f.w;
            uint2 p;
            p.x = f2bf(f.x) | (f2bf(f.y) << 16);
            p.y = f2bf(f.z) | (f2bf(f.w) << 16);
            int d4 = part * 8 + i;
            int byteoff = (row * 256 + d4 * 8) ^ ((row & 7) << 4);
            *(uint2*)((char*)As + byteoff) = p;
        }
        // reduce over the 4 parts (adjacent lanes) — 2 shuffles total
        ssq += __shfl_xor(ssq, 1);
        ssq += __shfl_xor(ssq, 2);
        if (part == 0) {
            if (c == 0) rnacc[row] = ssq;
            else        rnacc[row] += ssq;
        }

        // ---- process P ----
        #pragma unroll
        for (int i = 0; i < 4; ++i) {
            int q  = i * 512 + tid;
            int k  = q >> 4;
            int d8 = q & 15;
            int byteoff = (k * 256 + d8 * 16) ^ ((k & 7) << 4);
            *(uint4*)((char*)Ps + byteoff) = ubuf[i];
        }
        __syncthreads();

        // ---- MFMA: 4 k-steps of 32 d, wave owns 16 tokens ----
        #pragma unroll
        for (int ks = 0; ks < 4; ++ks) {
            const int kb = ks * 32;
            bf16x8 af;
            {
                int t = w * 16 + l15;
                int byteoff = (t * 256 + kb * 2 + l4 * 16) ^ ((t & 7) << 4);
                af = *(bf16x8*)((char*)As + byteoff);
            }
            bf16x8 pf[8];
            #pragma unroll
            for (int nt = 0; nt < 8; ++nt) {
                int k = nt * 16 + l15;
                int byteoff = (k * 256 + kb * 2 + l4 * 16) ^ ((k & 7) << 4);
                pf[nt] = *(bf16x8*)((char*)Ps + byteoff);
            }
            #pragma unroll
            for (int nt = 0; nt < 8; ++nt)
                acc[nt] = __builtin_amdgcn_mfma_f32_16x16x32_bf16(
                    af, pf[nt], acc[nt], 0, 0, 0);
        }
        __syncthreads();
    }

    // ---- finalize 1/norm ----
    if (tid < 128) rnacc[tid] = 1.0f / fmaxf(sqrtf(rnacc[tid]), 1e-6f);
    __syncthreads();

    // ---- epilogue 1: scaled C -> LDS (As reused) as fp16 [k][t], swizzled ----
    // C layout (verified R4): col = k = lane&15, row = t = (lane>>4)*4 + reg
    {
        const int tl = w * 16 + l4 * 4;
        float r0 = rnacc[tl + 0], r1 = rnacc[tl + 1];
        float r2 = rnacc[tl + 2], r3 = rnacc[tl + 3];
        #pragma unroll
        for (int nt = 0; nt < 8; ++nt) {
            int k = nt * 16 + l15;
            auto p0 = __builtin_amdgcn_cvt_pkrtz(acc[nt][0] * r0, acc[nt][1] * r1);
            auto p1 = __builtin_amdgcn_cvt_pkrtz(acc[nt][2] * r2, acc[nt][3] * r3);
            uint2 u;
            u.x = __builtin_bit_cast(u32, p0);
            u.y = __builtin_bit_cast(u32, p1);
            int byteoff = (k * 256 + tl * 2) ^ ((k & 7) << 4);
            *(uint2*)((char*)As + byteoff) = u;
        }
    }
    __syncthreads();

    // ---- epilogue 2: coalesced global write (256B per k-row contiguous) ----
    unsigned short* out = outh + (size_t)z * ((size_t)B_ * K_ * T_)
                               + (size_t)b * (K_ * T_) + ttile * 128;
    #pragma unroll
    for (int it = 0; it < 4; ++it) {
        int q    = it * 512 + tid;
        int krow = q >> 4;            // 16 uint4 per k-row
        int col  = q & 15;            // 8 tokens per uint4
        int byteoff = (krow * 256 + col * 16) ^ ((krow & 7) << 4);
        uint4 v = *(uint4*)((char*)As + byteoff);
        *(uint4*)(out + (size_t)krow * T_ + col * 8) = v;
    }
}

// ---------------------------------------------------------------------------
// Kernel 2: per-wave PACKED-fp16 register bitonic sort. (unchanged R11)
// ---------------------------------------------------------------------------
__device__ __forceinline__ u32 hmin2u(u32 a, u32 b) {
    h2 r = __builtin_elementwise_min(__builtin_bit_cast(h2, a),
                                     __builtin_bit_cast(h2, b));
    return __builtin_bit_cast(u32, r);
}
__device__ __forceinline__ u32 hmax2u(u32 a, u32 b) {
    h2 r = __builtin_elementwise_max(__builtin_bit_cast(h2, a),
                                     __builtin_bit_cast(h2, b));
    return __builtin_bit_cast(u32, r);
}
__device__ __forceinline__ u32 swap16(u32 x) {
    return __builtin_amdgcn_alignbit(x, x, 16);
}
__device__ __forceinline__ u32 blendlh(u32 hi_src, u32 lo_src) {
    return __builtin_amdgcn_perm(hi_src, lo_src, 0x07060100);
}

__device__ __forceinline__ void ce1A(u32& h) {
    u32 s = swap16(h), mn = hmin2u(h, s), mx = hmax2u(h, s);
    h = blendlh(mx, mn);
}
__device__ __forceinline__ void ce1D(u32& h) {
    u32 s = swap16(h), mn = hmin2u(h, s), mx = hmax2u(h, s);
    h = blendlh(mn, mx);
}
__device__ __forceinline__ void ce1U(u32& h, bool up) {
    u32 s = swap16(h), mn = hmin2u(h, s), mx = hmax2u(h, s);
    u32 A = blendlh(mx, mn), B = blendlh(mn, mx);
    h = up ? A : B;
}

__device__ __forceinline__ void cePA(u32& a, u32& b) {
    u32 mn = hmin2u(a, b), mx = hmax2u(a, b); a = mn; b = mx;
}
__device__ __forceinline__ void cePD(u32& a, u32& b) {
    u32 mn = hmin2u(a, b), mx = hmax2u(a, b); a = mx; b = mn;
}
__device__ __forceinline__ void cePU(u32& a, u32& b, bool up) {
    u32 mn = hmin2u(a, b), mx = hmax2u(a, b);
    a = up ? mn : mx; b = up ? mx : mn;
}

template <int M>
__device__ __forceinline__ void crossP(u32 h[8], bool keep) {
    #pragma unroll
    for (int r = 0; r < 8; ++r) {
        u32 o  = (u32)__shfl_xor((int)h[r], M);
        u32 mn = hmin2u(h[r], o), mx = hmax2u(h[r], o);
        h[r] = keep ? mn : mx;
    }
}

__device__ __forceinline__ void pre8P(u32 h[8]) {
    ce1A(h[0]); ce1D(h[1]); ce1A(h[2]); ce1D(h[3]);
    ce1A(h[4]); ce1D(h[5]); ce1A(h[6]); ce1D(h[7]);
    cePA(h[0], h[1]); cePD(h[2], h[3]); cePA(h[4], h[5]); cePD(h[6], h[7]);
    ce1A(h[0]); ce1A(h[1]); ce1D(h[2]); ce1D(h[3]);
    ce1A(h[4]); ce1A(h[5]); ce1D(h[6]); ce1D(h[7]);
    cePA(h[0], h[2]); cePA(h[1], h[3]); cePD(h[4], h[6]); cePD(h[5], h[7]);
    cePA(h[0], h[1]); cePA(h[2], h[3]); cePD(h[4], h[5]); cePD(h[6], h[7]);
    ce1A(h[0]); ce1A(h[1]); ce1A(h[2]); ce1A(h[3]);
    ce1D(h[4]); ce1D(h[5]); ce1D(h[6]); ce1D(h[7]);
}

__device__ __forceinline__ void intraPU(u32 h[8], bool up) {
    cePU(h[0], h[4], up); cePU(h[1], h[5], up);
    cePU(h[2], h[6], up); cePU(h[3], h[7], up);
    cePU(h[0], h[2], up); cePU(h[1], h[3], up);
    cePU(h[4], h[6], up); cePU(h[5], h[7], up);
    cePU(h[0], h[1], up); cePU(h[2], h[3], up);
    cePU(h[4], h[5], up); cePU(h[6], h[7], up);
    ce1U(h[0], up); ce1U(h[1], up); ce1U(h[2], up); ce1U(h[3], up);
    ce1U(h[4], up); ce1U(h[5], up); ce1U(h[6], up); ce1U(h[7], up);
}

__device__ __forceinline__ void intraPA(u32 h[8]) {
    cePA(h[0], h[4]); cePA(h[1], h[5]); cePA(h[2], h[6]); cePA(h[3], h[7]);
    cePA(h[0], h[2]); cePA(h[1], h[3]); cePA(h[4], h[6]); cePA(h[5], h[7]);
    cePA(h[0], h[1]); cePA(h[2], h[3]); cePA(h[4], h[5]); cePA(h[6], h[7]);
    ce1A(h[0]); ce1A(h[1]); ce1A(h[2]); ce1A(h[3]);
    ce1A(h[4]); ce1A(h[5]); ce1A(h[6]); ce1A(h[7]);
}

__global__ __launch_bounds__(256)
void sort_cost_kernel(const unsigned short* __restrict__ wsh,
                      float* __restrict__ cost) {
    const int wid  = threadIdx.x >> 6;
    const int lane = threadIdx.x & 63;
    const int bk   = blockIdx.x * 4 + wid;             // 0..8191

    const unsigned short* xr = wsh + (size_t)bk * T_;
    const unsigned short* yr = wsh + (size_t)(B_ * K_) * T_ + (size_t)bk * T_;

    u32 hx[8], hy[8];
    {
        const uint4* px = (const uint4*)(xr + lane * 16);
        uint4 a = px[0], b = px[1];
        hx[0] = a.x; hx[1] = a.y; hx[2] = a.z; hx[3] = a.w;
        hx[4] = b.x; hx[5] = b.y; hx[6] = b.z; hx[7] = b.w;
        const uint4* py = (const uint4*)(yr + lane * 16);
        uint4 c = py[0], d = py[1];
        hy[0] = c.x; hy[1] = c.y; hy[2] = c.z; hy[3] = c.w;
        hy[4] = d.x; hy[5] = d.y; hy[6] = d.z; hy[7] = d.w;
    }

    const bool b16  = (lane & 1)  == 0;
    const bool b32  = (lane & 2)  == 0;
    const bool b64  = (lane & 4)  == 0;
    const bool b128 = (lane & 8)  == 0;
    const bool b256 = (lane & 16) == 0;
    const bool b512 = (lane & 32) == 0;

    pre8P(hx); pre8P(hy);

    intraPU(hx, b16); intraPU(hy, b16);
    { const bool a = ((lane & 1) == 0) == b32;
      crossP<1>(hx, a); crossP<1>(hy, a); }
    intraPU(hx, b32); intraPU(hy, b32);
    { const bool a = ((lane & 2) == 0) == b64;
      crossP<2>(hx, a); crossP<2>(hy, a);
      const bool b = ((lane & 1) == 0) == b64;
      crossP<1>(hx, b); crossP<1>(hy, b); }
    intraPU(hx, b64); intraPU(hy, b64);
    { const bool a = ((lane & 4) == 0) == b128;
      crossP<4>(hx, a); crossP<4>(hy, a);
      const bool b = ((lane & 2) == 0) == b128;
      crossP<2>(hx, b); crossP<2>(hy, b);
      const bool c = ((lane & 1) == 0) == b128;
      crossP<1>(hx, c); crossP<1>(hy, c); }
    intraPU(hx, b128); intraPU(hy, b128);
    { const bool a = ((lane & 8) == 0) == b256;
      crossP<8>(hx, a); crossP<8>(hy, a);
      const bool b = ((lane & 4) == 0) == b256;
      crossP<4>(hx, b); crossP<4>(hy, b);
      const bool c = ((lane & 2) == 0) == b256;
      crossP<2>(hx, c); crossP<2>(hy, c);
      const bool d = ((lane & 1) == 0) == b256;
      crossP<1>(hx, d); crossP<1>(hy, d); }
    intraPU(hx, b256); intraPU(hy, b256);
    { const bool a = ((lane & 16) == 0) == b512;
      crossP<16>(hx, a); crossP<16>(hy, a);
      const bool b = ((lane & 8) == 0) == b512;
      crossP<8>(hx, b); crossP<8>(hy, b);
      const bool c = ((lane & 4) == 0) == b512;
      crossP<4>(hx, c); crossP<4>(hy, c);
      const bool d = ((lane & 2) == 0) == b512;
      crossP<2>(hx, d); crossP<2>(hy, d);
      const bool e = ((lane & 1) == 0) == b512;
      crossP<1>(hx, e); crossP<1>(hy, e); }
    intraPU(hx, b512); intraPU(hy, b512);
    { const bool a = (lane & 32) == 0;
      crossP<32>(hx, a); crossP<32>(hy, a);
      const bool b = (lane & 16) == 0;
      crossP<16>(hx, b); crossP<16>(hy, b);
      const bool c = (lane & 8) == 0;
      crossP<8>(hx, c); crossP<8>(hy, c);
      const bool d = (lane & 4) == 0;
      crossP<4>(hx, d); crossP<4>(hy, d);
      const bool e = (lane & 2) == 0;
      crossP<2>(hx, e); crossP<2>(hy, e);
      const bool f = (lane & 1) == 0;
      crossP<1>(hx, f); crossP<1>(hy, f); }
    intraPA(hx); intraPA(hy);

    float s = 0.0f;
    #pragma unroll
    for (int r = 0; r < 8; ++r) {
        h2 vx = __builtin_bit_cast(h2, hx[r]);
        h2 vy = __builtin_bit_cast(h2, hy[r]);
        float d0 = (float)vx[0] - (float)vy[0];
        float d1 = (float)vx[1] - (float)vy[1];
        s += d0 * d0 + d1 * d1;
    }
    #pragma unroll
    for (int m = 1; m <= 32; m <<= 1) s += __shfl_xor(s, m);
    if (lane == 0) cost[bk] = s;
}

// ---------------------------------------------------------------------------
// Kernel 3: sw[b] = sanitize(sqrt(sum_k cost / (K*T)))
// ---------------------------------------------------------------------------
__global__ void finalize_kernel(const float* __restrict__ cost,
                                float* __restrict__ out) {
    const int b = threadIdx.x;
    if (b >= B_) return;
    float s = 0.0f;
    for (int k = 0; k < K_; ++k) s += cost[b * K_ + k];
    float sw = sqrtf(s * (1.0f / (float)(K_ * T_)));
    if (isnan(sw)) sw = 1e4f;
    else if (isinf(sw)) sw = sw > 0.0f ? 1e4f : 0.0f;
    out[b] = sw;
}

extern "C" void kernel_launch(void* const* d_in, const int* in_sizes, int n_in,
                              void* d_out, int out_size, void* d_ws, size_t ws_size,
                              hipStream_t stream) {
    const float* x    = (const float*)d_in[0];
    const float* y    = (const float*)d_in[1];
    const float* proj = (const float*)d_in[2];
    // ws layout: [xp|yp] fp16 (32 MB), projT bf16 (64 KB), cost fp32 (32 KB)
    unsigned short* wsh = (unsigned short*)d_ws;
    unsigned short* pt  = wsh + (size_t)2 * B_ * K_ * T_;
    float* cost = (float*)(pt + (size_t)K_ * D_);
    float* out  = (float*)d_out;

    transpose_proj_kernel<<<(D_ * K_ + 255) / 256, 256, 0, stream>>>(proj, pt);
    proj_kernel<<<dim3(8, B_, 2), 512, 0, stream>>>(x, y, pt, wsh);
    sort_cost_kernel<<<(B_ * K_) / 4, 256, 0, stream>>>(wsh, cost);
    finalize_kernel<<<1, 64, 0, stream>>>(cost, out);
}

// Round 14
// 94.557 us; speedup vs baseline: 2.7912x; 1.1120x over previous
//
#include <hip/hip_runtime.h>
#include <hip/hip_bf16.h>

#define B_ 64
#define T_ 1024
#define D_ 256
#define K_ 128

typedef __attribute__((ext_vector_type(8))) short bf16x8;
typedef __attribute__((ext_vector_type(4))) float f32x4;
typedef __fp16 h2 __attribute__((ext_vector_type(2)));
typedef unsigned int u32;

__device__ __forceinline__ float san(float v) {
    if (isnan(v)) return 0.0f;
    if (isinf(v)) return v > 0.0f ? 1e4f : -1e4f;
    return v;
}

__device__ __forceinline__ float4 san4(float4 f) {
    f.x = san(f.x); f.y = san(f.y); f.z = san(f.z); f.w = san(f.w);
    return f;
}

// RNE float->bf16 (inputs pre-sanitized: no NaN/Inf)
__device__ __forceinline__ u32 f2bf(float f) {
    u32 u = __builtin_bit_cast(u32, f);
    u += 0x7fffu + ((u >> 16) & 1u);
    return u >> 16;
}

// ---------------------------------------------------------------------------
// Kernel 0: proj (D,K) fp32 -> projT (K,D) bf16  (tiny one-time transpose)
// ---------------------------------------------------------------------------
__global__ void transpose_proj_kernel(const float* __restrict__ proj,
                                      unsigned short* __restrict__ pt) {
    int e = blockIdx.x * 256 + threadIdx.x;       // 32768 elems
    if (e < D_ * K_) {
        int d = e >> 7, k = e & 127;
        pt[k * D_ + d] = (unsigned short)f2bf(proj[e]);
    }
}

// ---------------------------------------------------------------------------
// Kernel 1: fused sanitize + bf16 MFMA projection + deferred L2-normalize.
// (unchanged from R13 — ~43 us)
// ---------------------------------------------------------------------------
__global__ __launch_bounds__(512, 4)
void proj_kernel(const float* __restrict__ xin, const float* __restrict__ yin,
                 const unsigned short* __restrict__ pt,
                 unsigned short* __restrict__ outh) {
    __shared__ short As[128 * 128];   // 32 KB: A tile, then reused for C
    __shared__ short Ps[128 * 128];   // 32 KB
    __shared__ float rnacc[128];

    const int tid  = threadIdx.x;
    const int lane = tid & 63;
    const int w    = tid >> 6;        // wave 0..7
    const int ttile = blockIdx.x;     // 0..7
    const int b     = blockIdx.y;     // 0..63
    const int z     = blockIdx.z;     // 0=x 1=y

    const float* src = (z == 0 ? xin : yin)
                     + (size_t)b * (T_ * D_) + (size_t)ttile * 128 * D_;

    f32x4 acc[8];
    #pragma unroll
    for (int j = 0; j < 8; ++j) acc[j] = (f32x4){0.f, 0.f, 0.f, 0.f};

    const int l15 = lane & 15;
    const int l4  = lane >> 4;
    const int row  = tid >> 2;        // token row 0..127
    const int part = tid & 3;         // d-quarter (8 float4 each)

    for (int c = 0; c < 2; ++c) {
        const float4* rp = (const float4*)(src + row * D_ + c * 128 + part * 32);
        float4 fbuf[8];
        #pragma unroll
        for (int i = 0; i < 8; ++i) fbuf[i] = rp[i];
        uint4 ubuf[4];
        #pragma unroll
        for (int i = 0; i < 4; ++i) {
            int q  = i * 512 + tid;
            int k  = q >> 4;
            int d8 = q & 15;
            ubuf[i] = *(const uint4*)(pt + k * D_ + c * 128 + d8 * 8);
        }

        float ssq = 0.0f;
        #pragma unroll
        for (int i = 0; i < 8; ++i) {
            float4 f = san4(fbuf[i]);
            ssq += f.x * f.x + f.y * f.y + f.z * f.z + f.w * f.w;
            uint2 p;
            p.x = f2bf(f.x) | (f2bf(f.y) << 16);
            p.y = f2bf(f.z) | (f2bf(f.w) << 16);
            int d4 = part * 8 + i;
            int byteoff = (row * 256 + d4 * 8) ^ ((row & 7) << 4);
            *(uint2*)((char*)As + byteoff) = p;
        }
        ssq += __shfl_xor(ssq, 1);
        ssq += __shfl_xor(ssq, 2);
        if (part == 0) {
            if (c == 0) rnacc[row] = ssq;
            else        rnacc[row] += ssq;
        }

        #pragma unroll
        for (int i = 0; i < 4; ++i) {
            int q  = i * 512 + tid;
            int k  = q >> 4;
            int d8 = q & 15;
            int byteoff = (k * 256 + d8 * 16) ^ ((k & 7) << 4);
            *(uint4*)((char*)Ps + byteoff) = ubuf[i];
        }
        __syncthreads();

        #pragma unroll
        for (int ks = 0; ks < 4; ++ks) {
            const int kb = ks * 32;
            bf16x8 af;
            {
                int t = w * 16 + l15;
                int byteoff = (t * 256 + kb * 2 + l4 * 16) ^ ((t & 7) << 4);
                af = *(bf16x8*)((char*)As + byteoff);
            }
            bf16x8 pf[8];
            #pragma unroll
            for (int nt = 0; nt < 8; ++nt) {
                int k = nt * 16 + l15;
                int byteoff = (k * 256 + kb * 2 + l4 * 16) ^ ((k & 7) << 4);
                pf[nt] = *(bf16x8*)((char*)Ps + byteoff);
            }
            #pragma unroll
            for (int nt = 0; nt < 8; ++nt)
                acc[nt] = __builtin_amdgcn_mfma_f32_16x16x32_bf16(
                    af, pf[nt], acc[nt], 0, 0, 0);
        }
        __syncthreads();
    }

    if (tid < 128) rnacc[tid] = 1.0f / fmaxf(sqrtf(rnacc[tid]), 1e-6f);
    __syncthreads();

    // epilogue 1: scaled C -> LDS as fp16 [k][t], swizzled
    {
        const int tl = w * 16 + l4 * 4;
        float r0 = rnacc[tl + 0], r1 = rnacc[tl + 1];
        float r2 = rnacc[tl + 2], r3 = rnacc[tl + 3];
        #pragma unroll
        for (int nt = 0; nt < 8; ++nt) {
            int k = nt * 16 + l15;
            auto p0 = __builtin_amdgcn_cvt_pkrtz(acc[nt][0] * r0, acc[nt][1] * r1);
            auto p1 = __builtin_amdgcn_cvt_pkrtz(acc[nt][2] * r2, acc[nt][3] * r3);
            uint2 u;
            u.x = __builtin_bit_cast(u32, p0);
            u.y = __builtin_bit_cast(u32, p1);
            int byteoff = (k * 256 + tl * 2) ^ ((k & 7) << 4);
            *(uint2*)((char*)As + byteoff) = u;
        }
    }
    __syncthreads();

    // epilogue 2: coalesced global write
    unsigned short* out = outh + (size_t)z * ((size_t)B_ * K_ * T_)
                               + (size_t)b * (K_ * T_) + ttile * 128;
    #pragma unroll
    for (int it = 0; it < 4; ++it) {
        int q    = it * 512 + tid;
        int krow = q >> 4;
        int col  = q & 15;
        int byteoff = (krow * 256 + col * 16) ^ ((krow & 7) << 4);
        uint4 v = *(uint4*)((char*)As + byteoff);
        *(uint4*)(out + (size_t)krow * T_ + col * 8) = v;
    }
}

// ---------------------------------------------------------------------------
// Kernel 2: packed-fp16 bitonic sort, ONE SEQUENCE PER WAVE.
// Block = 4 waves: waves 0,1 sort x of pairs (2*bid, 2*bid+1); waves 2,3
// sort the matching y and park results in LDS; x-waves diff in-register
// sorted x against LDS y. Min/max forced to v_pk_*_f16 via inline asm.
// Element id e = lane*16 + reg*2 + half (same verified mapping as R11).
// ---------------------------------------------------------------------------
__device__ __forceinline__ u32 pkmin(u32 a, u32 b) {
    u32 r;
    asm("v_pk_min_f16 %0, %1, %2" : "=v"(r) : "v"(a), "v"(b));
    return r;
}
__device__ __forceinline__ u32 pkmax(u32 a, u32 b) {
    u32 r;
    asm("v_pk_max_f16 %0, %1, %2" : "=v"(r) : "v"(a), "v"(b));
    return r;
}
__device__ __forceinline__ u32 swap16(u32 x) {
    return __builtin_amdgcn_alignbit(x, x, 16);
}
// {lo: lo_src.lo, hi: hi_src.hi}
__device__ __forceinline__ u32 blendlh(u32 hi_src, u32 lo_src) {
    return __builtin_amdgcn_perm(hi_src, lo_src, 0x07060100);
}

__device__ __forceinline__ void ce1A(u32& h) {
    u32 s = swap16(h), mn = pkmin(h, s), mx = pkmax(h, s);
    h = blendlh(mx, mn);
}
__device__ __forceinline__ void ce1D(u32& h) {
    u32 s = swap16(h), mn = pkmin(h, s), mx = pkmax(h, s);
    h = blendlh(mn, mx);
}
__device__ __forceinline__ void ce1U(u32& h, bool up) {
    u32 s = swap16(h), mn = pkmin(h, s), mx = pkmax(h, s);
    u32 A = blendlh(mx, mn), B = blendlh(mn, mx);
    h = up ? A : B;
}

__device__ __forceinline__ void cePA(u32& a, u32& b) {
    u32 mn = pkmin(a, b), mx = pkmax(a, b); a = mn; b = mx;
}
__device__ __forceinline__ void cePD(u32& a, u32& b) {
    u32 mn = pkmin(a, b), mx = pkmax(a, b); a = mx; b = mn;
}
__device__ __forceinline__ void cePU(u32& a, u32& b, bool up) {
    u32 mn = pkmin(a, b), mx = pkmax(a, b);
    a = up ? mn : mx; b = up ? mx : mn;
}

template <int M>
__device__ __forceinline__ void crossP(u32 h[8], bool keep) {
    #pragma unroll
    for (int r = 0; r < 8; ++r) {
        u32 o  = (u32)__shfl_xor((int)h[r], M);
        u32 mn = pkmin(h[r], o), mx = pkmax(h[r], o);
        h[r] = keep ? mn : mx;
    }
}

__device__ __forceinline__ void pre8P(u32 h[8]) {
    ce1A(h[0]); ce1D(h[1]); ce1A(h[2]); ce1D(h[3]);
    ce1A(h[4]); ce1D(h[5]); ce1A(h[6]); ce1D(h[7]);
    cePA(h[0], h[1]); cePD(h[2], h[3]); cePA(h[4], h[5]); cePD(h[6], h[7]);
    ce1A(h[0]); ce1A(h[1]); ce1D(h[2]); ce1D(h[3]);
    ce1A(h[4]); ce1A(h[5]); ce1D(h[6]); ce1D(h[7]);
    cePA(h[0], h[2]); cePA(h[1], h[3]); cePD(h[4], h[6]); cePD(h[5], h[7]);
    cePA(h[0], h[1]); cePA(h[2], h[3]); cePD(h[4], h[5]); cePD(h[6], h[7]);
    ce1A(h[0]); ce1A(h[1]); ce1A(h[2]); ce1A(h[3]);
    ce1D(h[4]); ce1D(h[5]); ce1D(h[6]); ce1D(h[7]);
}

__device__ __forceinline__ void intraPU(u32 h[8], bool up) {
    cePU(h[0], h[4], up); cePU(h[1], h[5], up);
    cePU(h[2], h[6], up); cePU(h[3], h[7], up);
    cePU(h[0], h[2], up); cePU(h[1], h[3], up);
    cePU(h[4], h[6], up); cePU(h[5], h[7], up);
    cePU(h[0], h[1], up); cePU(h[2], h[3], up);
    cePU(h[4], h[5], up); cePU(h[6], h[7], up);
    ce1U(h[0], up); ce1U(h[1], up); ce1U(h[2], up); ce1U(h[3], up);
    ce1U(h[4], up); ce1U(h[5], up); ce1U(h[6], up); ce1U(h[7], up);
}

__device__ __forceinline__ void intraPA(u32 h[8]) {
    cePA(h[0], h[4]); cePA(h[1], h[5]); cePA(h[2], h[6]); cePA(h[3], h[7]);
    cePA(h[0], h[2]); cePA(h[1], h[3]); cePA(h[4], h[6]); cePA(h[5], h[7]);
    cePA(h[0], h[1]); cePA(h[2], h[3]); cePA(h[4], h[5]); cePA(h[6], h[7]);
    ce1A(h[0]); ce1A(h[1]); ce1A(h[2]); ce1A(h[3]);
    ce1A(h[4]); ce1A(h[5]); ce1A(h[6]); ce1A(h[7]);
}

// full bitonic sort of one 1024-seq held as h[8] (2 fp16/reg/lane)
__device__ __forceinline__ void sort1024(u32 h[8], int lane) {
    const bool b16  = (lane & 1)  == 0;
    const bool b32  = (lane & 2)  == 0;
    const bool b64  = (lane & 4)  == 0;
    const bool b128 = (lane & 8)  == 0;
    const bool b256 = (lane & 16) == 0;
    const bool b512 = (lane & 32) == 0;

    pre8P(h);
    intraPU(h, b16);
    { const bool a = ((lane & 1) == 0) == b32;  crossP<1>(h, a); }
    intraPU(h, b32);
    { const bool a = ((lane & 2) == 0) == b64;  crossP<2>(h, a);
      const bool b = ((lane & 1) == 0) == b64;  crossP<1>(h, b); }
    intraPU(h, b64);
    { const bool a = ((lane & 4) == 0) == b128; crossP<4>(h, a);
      const bool b = ((lane & 2) == 0) == b128; crossP<2>(h, b);
      const bool c = ((lane & 1) == 0) == b128; crossP<1>(h, c); }
    intraPU(h, b128);
    { const bool a = ((lane & 8) == 0) == b256; crossP<8>(h, a);
      const bool b = ((lane & 4) == 0) == b256; crossP<4>(h, b);
      const bool c = ((lane & 2) == 0) == b256; crossP<2>(h, c);
      const bool d = ((lane & 1) == 0) == b256; crossP<1>(h, d); }
    intraPU(h, b256);
    { const bool a = ((lane & 16) == 0) == b512; crossP<16>(h, a);
      const bool b = ((lane & 8) == 0)  == b512; crossP<8>(h, b);
      const bool c = ((lane & 4) == 0)  == b512; crossP<4>(h, c);
      const bool d = ((lane & 2) == 0)  == b512; crossP<2>(h, d);
      const bool e = ((lane & 1) == 0)  == b512; crossP<1>(h, e); }
    intraPU(h, b512);
    { const bool a = (lane & 32) == 0; crossP<32>(h, a);
      const bool b = (lane & 16) == 0; crossP<16>(h, b);
      const bool c = (lane & 8) == 0;  crossP<8>(h, c);
      const bool d = (lane & 4) == 0;  crossP<4>(h, d);
      const bool e = (lane & 2) == 0;  crossP<2>(h, e);
      const bool f = (lane & 1) == 0;  crossP<1>(h, f); }
    intraPA(h);
}

__global__ __launch_bounds__(256)
void sort_cost_kernel(const unsigned short* __restrict__ wsh,
                      float* __restrict__ cost) {
    __shared__ u32 yl[2][8][64];                 // sorted y, 4 KB

    const int w    = threadIdx.x >> 6;           // wave 0..3
    const int lane = threadIdx.x & 63;
    const int pr   = blockIdx.x * 2 + (w & 1);   // pair 0..8191
    const bool isy = (w >= 2);

    const unsigned short* base = wsh
        + (isy ? (size_t)(B_ * K_) * T_ : (size_t)0) + (size_t)pr * T_;

    u32 h[8];
    {
        const uint4* p = (const uint4*)(base + lane * 16);
        uint4 a = p[0], b = p[1];
        h[0] = a.x; h[1] = a.y; h[2] = a.z; h[3] = a.w;
        h[4] = b.x; h[5] = b.y; h[6] = b.z; h[7] = b.w;
    }

    sort1024(h, lane);

    if (isy) {
        #pragma unroll
        for (int r = 0; r < 8; ++r) yl[w & 1][r][lane] = h[r];
    }
    __syncthreads();

    if (!isy) {
        float s = 0.0f;
        #pragma unroll
        for (int r = 0; r < 8; ++r) {
            u32 yv = yl[w][r][lane];
            h2 vx = __builtin_bit_cast(h2, h[r]);
            h2 vy = __builtin_bit_cast(h2, yv);
            float d0 = (float)vx[0] - (float)vy[0];
            float d1 = (float)vx[1] - (float)vy[1];
            s += d0 * d0 + d1 * d1;
        }
        #pragma unroll
        for (int m = 1; m <= 32; m <<= 1) s += __shfl_xor(s, m);
        if (lane == 0) cost[pr] = s;
    }
}

// ---------------------------------------------------------------------------
// Kernel 3: sw[b] = sanitize(sqrt(sum_k cost / (K*T)))
// ---------------------------------------------------------------------------
__global__ void finalize_kernel(const float* __restrict__ cost,
                                float* __restrict__ out) {
    const int b = threadIdx.x;
    if (b >= B_) return;
    float s = 0.0f;
    for (int k = 0; k < K_; ++k) s += cost[b * K_ + k];
    float sw = sqrtf(s * (1.0f / (float)(K_ * T_)));
    if (isnan(sw)) sw = 1e4f;
    else if (isinf(sw)) sw = sw > 0.0f ? 1e4f : 0.0f;
    out[b] = sw;
}

extern "C" void kernel_launch(void* const* d_in, const int* in_sizes, int n_in,
                              void* d_out, int out_size, void* d_ws, size_t ws_size,
                              hipStream_t stream) {
    const float* x    = (const float*)d_in[0];
    const float* y    = (const float*)d_in[1];
    const float* proj = (const float*)d_in[2];
    // ws layout: [xp|yp] fp16 (32 MB), projT bf16 (64 KB), cost fp32 (32 KB)
    unsigned short* wsh = (unsigned short*)d_ws;
    unsigned short* pt  = wsh + (size_t)2 * B_ * K_ * T_;
    float* cost = (float*)(pt + (size_t)K_ * D_);
    float* out  = (float*)d_out;

    transpose_proj_kernel<<<(D_ * K_ + 255) / 256, 256, 0, stream>>>(proj, pt);
    proj_kernel<<<dim3(8, B_, 2), 512, 0, stream>>>(x, y, pt, wsh);
    sort_cost_kernel<<<(B_ * K_) / 2, 256, 0, stream>>>(wsh, cost);
    finalize_kernel<<<1, 64, 0, stream>>>(cost, out);
}